// Round 7
// baseline (410.724 us; speedup 1.0000x reference)
//
#include <hip/hip_runtime.h>
#include <stdint.h>

// Problem dims (fixed by the reference)
constexpr int B_ = 2, S_ = 2048, E_ = 1024, H_ = 16, D_ = 64;
constexpr int M_ = B_ * S_;              // 4096 rows

typedef unsigned short u16;
typedef __attribute__((ext_vector_type(8))) short short8;
typedef __attribute__((ext_vector_type(4))) float f32x4;

__device__ __forceinline__ u16 f2bf(float f) {
  uint32_t u = __float_as_uint(f);
  return (u16)((u + 0x7FFFu + ((u >> 16) & 1u)) >> 16);  // RNE
}
// truncation split: hi = trunc16(x), lo = trunc16(x - hi). hi+lo ~ x to 2^-17.
__device__ __forceinline__ void tsplit(float x, u16& hi, u16& lo) {
  const uint32_t u = __float_as_uint(x);
  hi = (u16)(u >> 16);
  const float hif = __uint_as_float(u & 0xFFFF0000u);
  lo = (u16)(__float_as_uint(x - hif) >> 16);
}

// ---------------------------------------------------------------------------
// Kernel 0: split fp32 -> (hi, lo) bf16 pair, elementwise (weights).
// ---------------------------------------------------------------------------
__global__ __launch_bounds__(256) void split_f32_kernel(
    const float* __restrict__ src, u16* __restrict__ hi, u16* __restrict__ lo, int n4)
{
  const int i = blockIdx.x * 256 + threadIdx.x;
  if (i >= n4) return;
  const float4 x = ((const float4*)src)[i];
  ushort4 h, l;
  tsplit(x.x, h.x, l.x); tsplit(x.y, h.y, l.y);
  tsplit(x.z, h.z, l.z); tsplit(x.w, h.w, l.w);
  ((ushort4*)hi)[i] = h;
  ((ushort4*)lo)[i] = l;
}

// ---------------------------------------------------------------------------
// Kernel 0b: per-batch scan of key mask -> opos (compact slot j -> orig row s)
// and nk[b] (# unmasked keys).
// ---------------------------------------------------------------------------
__global__ __launch_bounds__(256) void mask_scan_kernel(
    const int* __restrict__ mask, int* __restrict__ opos, int* __restrict__ nk)
{
  __shared__ int tmp[256];
  __shared__ int coff;
  const int b = blockIdx.x, t = threadIdx.x;
  for (int c = t; c < S_; c += 256) opos[b * S_ + c] = 0;  // safe default
  if (t == 0) coff = 0;
  __syncthreads();
  for (int c = 0; c < S_; c += 256) {
    const int m = (mask[b * S_ + c + t] != 0) ? 1 : 0;
    int x = m;
    tmp[t] = x;
    __syncthreads();
#pragma unroll
    for (int off = 1; off < 256; off <<= 1) {
      const int v = (t >= off) ? tmp[t - off] : 0;
      __syncthreads();
      x += v;
      tmp[t] = x;
      __syncthreads();
    }
    const int base = coff;
    if (m) opos[b * S_ + base + x - 1] = c + t;  // scatter: slot -> orig row
    __syncthreads();
    if (t == 255) coff = base + x;
    __syncthreads();
  }
  if (t == 0) nk[b] = coff;
}

// ---------------------------------------------------------------------------
// Kernel 1: QKV projection. v7: DIRECT-FROM-GLOBAL operand streaming.
// No LDS / no barriers in the main loop: each lane's MFMA fragments are
// contiguous 16-32B runs in global (A row-major fp32, W pre-split bf16),
// loaded directly and converted in-register. Waves fully independent.
// Tile: 128x128 per block, 4 waves (2m x 2n), wave = 64x64 (acc[4][4]).
// K/V input rows gathered through opos (compaction); blocks past nk exit.
// Epilogue: Q/K via per-wave LDS transpose (no cross-wave sync needed);
// V scatter-stores to [B,H,D,S] compacted.
// ---------------------------------------------------------------------------
__global__ __launch_bounds__(256) void gemm_qkv_kernel(
    const float* __restrict__ q, const float* __restrict__ k, const float* __restrict__ v,
    const u16* __restrict__ WHi, const u16* __restrict__ WLo,
    const float* __restrict__ bias,
    const int* __restrict__ Opos, const int* __restrict__ NkArr,
    u16* __restrict__ QpHi, u16* __restrict__ QpLo,
    u16* __restrict__ KpHi, u16* __restrict__ KpLo,
    u16* __restrict__ Vp)
{
  __shared__ __align__(16) short T[4 * 4608];  // per-wave [64][72], epilogue only

  const int t = threadIdx.x;
  const int m0 = blockIdx.x * 128;
  const int n0g = blockIdx.y * 128;          // global col in [0, 3072)
  const int proj = n0g >> 10;
  const int nloc = n0g & (E_ - 1);
  const bool split = (proj < 2);
  const int bb = m0 >> 11, mloc = m0 & (S_ - 1);
  const int nkb = NkArr[bb];
  if (proj != 0 && mloc >= nkb) return;      // compacted K/V: nothing to do

  const float* A = (proj == 0) ? q : (proj == 1) ? k : v;

  const int w = t >> 6, lane = t & 63;
  const int g = lane >> 4, lc = lane & 15;
  const int wm = w & 1, wn = w >> 1;

  // per-lane A row pointers (gathered through opos for K/V), k-offset +8g
  const float* Arow[4];
#pragma unroll
  for (int mt = 0; mt < 4; ++mt) {
    int r;
    if (proj == 0) r = m0 + wm * 64 + mt * 16 + lc;
    else {
      const int slot = mloc + wm * 64 + mt * 16 + lc;
      r = bb * S_ + (Opos[bb * S_ + slot] & (S_ - 1));
    }
    Arow[mt] = A + (size_t)r * E_ + 8 * g;
  }
  // per-lane B row pointers (weight rows = output cols), k-offset +8g
  const u16* BrowH[4];
  const u16* BrowL[4];
#pragma unroll
  for (int nt = 0; nt < 4; ++nt) {
    const int c = n0g + wn * 64 + nt * 16 + lc;
    BrowH[nt] = WHi + (size_t)c * E_ + 8 * g;
    BrowL[nt] = WLo + (size_t)c * E_ + 8 * g;
  }

  f32x4 acc[4][4];
#pragma unroll
  for (int i = 0; i < 4; ++i)
#pragma unroll
    for (int j = 0; j < 4; ++j) acc[i][j] = (f32x4){0.f, 0.f, 0.f, 0.f};

  for (int k0 = 0; k0 < E_; k0 += 32) {
    // ---- A fragments: 8 f32 per lane, split to bf16 hi/lo in-register ----
    short8 ah[4], al[4];
#pragma unroll
    for (int mt = 0; mt < 4; ++mt) {
      const float4 xa = *(const float4*)(Arow[mt] + k0);
      const float4 xb = *(const float4*)(Arow[mt] + k0 + 4);
      const float xs[8] = {xa.x, xa.y, xa.z, xa.w, xb.x, xb.y, xb.z, xb.w};
      short8 h8, l8;
#pragma unroll
      for (int j = 0; j < 8; ++j) {
        const uint32_t u = __float_as_uint(xs[j]);
        h8[j] = (short)(u >> 16);
        if (split) {
          const float hif = __uint_as_float(u & 0xFFFF0000u);
          l8[j] = (short)(__float_as_uint(xs[j] - hif) >> 16);
        } else {
          l8[j] = 0;
        }
      }
      ah[mt] = h8;
      al[mt] = l8;
    }
    // ---- B fragments: direct 16B loads (pre-split bf16) ----
    short8 bh[4], bl[4];
#pragma unroll
    for (int nt = 0; nt < 4; ++nt) {
      bh[nt] = *(const short8*)(BrowH[nt] + k0);
      if (split) bl[nt] = *(const short8*)(BrowL[nt] + k0);
    }
    // ---- MFMAs ----
#pragma unroll
    for (int mt = 0; mt < 4; ++mt)
#pragma unroll
      for (int nt = 0; nt < 4; ++nt) {
        f32x4 a = acc[mt][nt];
        a = __builtin_amdgcn_mfma_f32_16x16x32_bf16(ah[mt], bh[nt], a, 0, 0, 0);
        if (split) {
          a = __builtin_amdgcn_mfma_f32_16x16x32_bf16(ah[mt], bl[nt], a, 0, 0, 0);
          a = __builtin_amdgcn_mfma_f32_16x16x32_bf16(al[mt], bh[nt], a, 0, 0, 0);
        }
        acc[mt][nt] = a;
      }
  }

  // ---- epilogue ----
  float bs[4];
#pragma unroll
  for (int nt = 0; nt < 4; ++nt) bs[nt] = bias[n0g + wn * 64 + nt * 16 + lc];

  if (proj < 2) {
    // wave's 64 n-cols = exactly one head: head = (nloc>>6) + wn, d = 0..63.
    // Per-wave transpose buffer; no cross-wave synchronization needed.
    u16* Hi = (proj == 0) ? QpHi : KpHi;
    u16* Lo = (proj == 0) ? QpLo : KpLo;
    const int head = (nloc >> 6) + wn;
    short* Tw = T + w * 4608;                 // [64][72] u16
    const int srow = mloc + wm * 64 + lane;   // output row (compact for K)
    const size_t rowb = (((size_t)(bb * H_ + head)) * S_ + srow) * D_;
#pragma unroll
    for (int pass = 0; pass < 2; ++pass) {
#pragma unroll
      for (int nt = 0; nt < 4; ++nt)
#pragma unroll
        for (int mt = 0; mt < 4; ++mt)
#pragma unroll
          for (int r = 0; r < 4; ++r) {
            const float val = acc[mt][nt][r] + bs[nt];
            const uint32_t u = __float_as_uint(val);
            u16 x;
            if (pass == 0) x = (u16)(u >> 16);
            else {
              const float hif = __uint_as_float(u & 0xFFFF0000u);
              x = (u16)(__float_as_uint(val - hif) >> 16);
            }
            Tw[(mt * 16 + g * 4 + r) * 72 + nt * 16 + lc] = (short)x;
          }
      u16* dst = (pass == 0) ? Hi : Lo;
#pragma unroll
      for (int j = 0; j < 8; ++j)
        *(short8*)&dst[rowb + 8 * j] = *(const short8*)&Tw[lane * 72 + 8 * j];
    }
  } else {
    // V: [B,H,D,S] layout, compact key columns; predicate j < nk (tail stays 0)
#pragma unroll
    for (int mt = 0; mt < 4; ++mt) {
      const int jb = mloc + wm * 64 + mt * 16 + g * 4;
#pragma unroll
      for (int nt = 0; nt < 4; ++nt) {
        const int nE = nloc + wn * 64 + nt * 16 + lc;
        const int h = nE >> 6, d = nE & 63;
        const size_t rb = (((size_t)(bb * H_ + h)) * D_ + d) * S_;
#pragma unroll
        for (int r = 0; r < 4; ++r) {
          if (jb + r < nkb) Vp[rb + jb + r] = f2bf(acc[mt][nt][r] + bs[nt]);
        }
      }
    }
  }
}

// ---------------------------------------------------------------------------
// Kernel 2: MFMA flash attention (unchanged from round 6, which passed).
// ---------------------------------------------------------------------------
__device__ __forceinline__ void block_sync() {
  asm volatile("s_waitcnt lgkmcnt(0)" ::: "memory");
  __builtin_amdgcn_s_barrier();
}

__global__ __launch_bounds__(256, 4) void attn_mfma_kernel(
    const u16* __restrict__ QpHi, const u16* __restrict__ QpLo,
    const u16* __restrict__ KpHi, const u16* __restrict__ KpLo,
    const u16* __restrict__ Vp,
    const int* __restrict__ nkArr,
    u16* __restrict__ AOHi)
{
  __shared__ __align__(16) short sm[18432];  // 36,864 B
  short* Khi = sm;                           // [64][72]
  short* Klo = sm + 4608;                    // [64][72]
  short* Vt  = sm + 9216;                    // [64][72] (d-major)
  short* Pb  = sm + 13824;                   // 4 waves x [16][72]

  const int t = threadIdx.x;
  const int w = t >> 6, lane = t & 63;
  const int g = lane >> 4, lc = lane & 15;
  const int bh = blockIdx.y;
  const int b = bh >> 4, hh = bh & 15;
  const int q0 = blockIdx.x * 64;
  const size_t hb = (size_t)bh * S_ * D_;
  const u16* QgH = QpHi + hb;
  const u16* QgL = QpLo + hb;
  const u16* KgH = KpHi + hb;
  const u16* KgL = KpLo + hb;
  const u16* Vg  = Vp + hb;
  short* Pw = Pb + w * 1152;

  const int nk = nkArr[b];
  const int kend = ((nk + 63) >> 6) << 6;    // tiles of 64 compacted keys

  // ---- Q A-frags direct from global (lane lc = q-row, k = 8g..8g+7) ----
  short8 qh[2], ql[2];
  {
    const size_t base = (size_t)(q0 + 16 * w + lc) * D_ + 8 * g;
    qh[0] = *(const short8*)&QgH[base];
    qh[1] = *(const short8*)&QgH[base + 32];
    ql[0] = *(const short8*)&QgL[base];
    ql[1] = *(const short8*)&QgL[base + 32];
  }

  // ones column in B (n=0): lanes with lc==0 hold bf16(1.0) for all k
  short8 ones8 = {0, 0, 0, 0, 0, 0, 0, 0};
  if (lc == 0) {
    const short o = (short)0x3F80;
    ones8 = (short8){o, o, o, o, o, o, o, o};
  }

  f32x4 O[4];
  f32x4 Ol = (f32x4){0.f, 0.f, 0.f, 0.f};
#pragma unroll
  for (int dt = 0; dt < 4; ++dt) O[dt] = (f32x4){0.f, 0.f, 0.f, 0.f};
  float mst[4] = {-INFINITY, -INFINITY, -INFINITY, -INFINITY};

  const int srow = t >> 2, sc16 = (t & 3) * 16;   // staging: 4 threads/row

  // staging prefetch registers (K hi/lo, V)
  short8 kr[2], lr[2], vr[2];
  kr[0] = *(const short8*)&KgH[srow * D_ + sc16];
  kr[1] = *(const short8*)&KgH[srow * D_ + sc16 + 8];
  lr[0] = *(const short8*)&KgL[srow * D_ + sc16];
  lr[1] = *(const short8*)&KgL[srow * D_ + sc16 + 8];
  vr[0] = *(const short8*)&Vg[srow * S_ + sc16];
  vr[1] = *(const short8*)&Vg[srow * S_ + sc16 + 8];

  for (int kt = 0; kt < kend; kt += 64) {
    block_sync();                            // previous tile fully consumed
    *(short8*)&Khi[srow * 72 + sc16]     = kr[0];
    *(short8*)&Khi[srow * 72 + sc16 + 8] = kr[1];
    *(short8*)&Klo[srow * 72 + sc16]     = lr[0];
    *(short8*)&Klo[srow * 72 + sc16 + 8] = lr[1];
    *(short8*)&Vt[srow * 72 + sc16]      = vr[0];
    *(short8*)&Vt[srow * 72 + sc16 + 8]  = vr[1];
    block_sync();
    if (kt + 64 < kend) {                    // prefetch next tile
      const int kn = kt + 64;
      kr[0] = *(const short8*)&KgH[(kn + srow) * D_ + sc16];
      kr[1] = *(const short8*)&KgH[(kn + srow) * D_ + sc16 + 8];
      lr[0] = *(const short8*)&KgL[(kn + srow) * D_ + sc16];
      lr[1] = *(const short8*)&KgL[(kn + srow) * D_ + sc16 + 8];
      vr[0] = *(const short8*)&Vg[srow * S_ + kn + sc16];
      vr[1] = *(const short8*)&Vg[srow * S_ + kn + sc16 + 8];
    }

    // ---- scores: S[16q x 64k] ----
    f32x4 sc[4];
#pragma unroll
    for (int kt16 = 0; kt16 < 4; ++kt16) {
      const int ko = (16 * kt16 + lc) * 72 + 8 * g;
      const short8 kh0 = *(const short8*)&Khi[ko];
      const short8 kh1 = *(const short8*)&Khi[ko + 32];
      const short8 kl0 = *(const short8*)&Klo[ko];
      const short8 kl1 = *(const short8*)&Klo[ko + 32];
      f32x4 a = {0.f, 0.f, 0.f, 0.f};
      a = __builtin_amdgcn_mfma_f32_16x16x32_bf16(qh[0], kh0, a, 0, 0, 0);
      a = __builtin_amdgcn_mfma_f32_16x16x32_bf16(qh[1], kh1, a, 0, 0, 0);
      a = __builtin_amdgcn_mfma_f32_16x16x32_bf16(qh[0], kl0, a, 0, 0, 0);
      a = __builtin_amdgcn_mfma_f32_16x16x32_bf16(qh[1], kl1, a, 0, 0, 0);
      a = __builtin_amdgcn_mfma_f32_16x16x32_bf16(ql[0], kh0, a, 0, 0, 0);
      a = __builtin_amdgcn_mfma_f32_16x16x32_bf16(ql[1], kh1, a, 0, 0, 0);
      sc[kt16] = a;
    }

    // ---- tail masking: compacted cols >= nk are padding (garbage K) ----
    if (kt + 64 > nk) {
#pragma unroll
      for (int kt16 = 0; kt16 < 4; ++kt16) {
        if (kt + 16 * kt16 + lc >= nk) {
          sc[kt16][0] = -1e20f; sc[kt16][1] = -1e20f;
          sc[kt16][2] = -1e20f; sc[kt16][3] = -1e20f;
        }
      }
    }

    // ---- online max + exp (max butterfly only; sum comes from MFMA) ----
    float al[4];
#pragma unroll
    for (int r = 0; r < 4; ++r) {
      float vv = fmaxf(fmaxf(sc[0][r], sc[1][r]), fmaxf(sc[2][r], sc[3][r]));
      vv = fmaxf(vv, __shfl_xor(vv, 1));
      vv = fmaxf(vv, __shfl_xor(vv, 2));
      vv = fmaxf(vv, __shfl_xor(vv, 4));
      vv = fmaxf(vv, __shfl_xor(vv, 8));
      const float mn = fmaxf(mst[r], vv);
      al[r] = __expf(mst[r] - mn);           // first tile: exp(-inf)=0
      mst[r] = mn;
    }
#pragma unroll
    for (int kt16 = 0; kt16 < 4; ++kt16) {
#pragma unroll
      for (int r = 0; r < 4; ++r)
        sc[kt16][r] = __expf(sc[kt16][r] - mst[r]);
    }
    const f32x4 alv = {al[0], al[1], al[2], al[3]};
    O[0] *= alv; O[1] *= alv; O[2] *= alv; O[3] *= alv;
    Ol *= alv;
    // P: C-layout regs -> bf16 LDS (A-layout source for PV)
#pragma unroll
    for (int kt16 = 0; kt16 < 4; ++kt16) {
#pragma unroll
      for (int r = 0; r < 4; ++r)
        Pw[(4 * g + r) * 72 + 16 * kt16 + lc] = (short)f2bf(sc[kt16][r]);
    }

    // ---- PV + denominator via ones ----
    short8 pa[2];
    pa[0] = *(const short8*)&Pw[lc * 72 + 8 * g];
    pa[1] = *(const short8*)&Pw[lc * 72 + 32 + 8 * g];
    Ol = __builtin_amdgcn_mfma_f32_16x16x32_bf16(pa[0], ones8, Ol, 0, 0, 0);
    Ol = __builtin_amdgcn_mfma_f32_16x16x32_bf16(pa[1], ones8, Ol, 0, 0, 0);
#pragma unroll
    for (int dt = 0; dt < 4; ++dt) {
      const int vo = (16 * dt + lc) * 72 + 8 * g;
      const short8 vb0 = *(const short8*)&Vt[vo];
      const short8 vb1 = *(const short8*)&Vt[vo + 32];
      O[dt] = __builtin_amdgcn_mfma_f32_16x16x32_bf16(pa[0], vb0, O[dt], 0, 0, 0);
      O[dt] = __builtin_amdgcn_mfma_f32_16x16x32_bf16(pa[1], vb1, O[dt], 0, 0, 0);
    }
  }

  // ---- epilogue: broadcast denominator (col 0 on lanes lc==0), normalize ----
#pragma unroll
  for (int r = 0; r < 4; ++r) {
    const float lv = __shfl(Ol[r], lane & 48);
    const float lir = 1.0f / lv;
    const int qrow = q0 + 16 * w + 4 * g + r;
    const size_t rowb = (size_t)(b * S_ + qrow) * E_ + hh * 64;
#pragma unroll
    for (int dt = 0; dt < 4; ++dt)
      AOHi[rowb + dt * 16 + lc] = f2bf(O[dt][r] * lir);
  }
}

// ---------------------------------------------------------------------------
// Kernel 3: output projection. v6: direct-from-global streaming, no LDS,
// no barriers. Block 128x64, 4 waves (2m x 2n), wave = 64x32 (acc[4][2]).
// A (AOHi) and B (WoutHi) are bf16 row-major: fragments load directly.
// ---------------------------------------------------------------------------
__global__ __launch_bounds__(256) void gemm_out_kernel(
    const u16* __restrict__ AHi,
    const u16* __restrict__ WHi,
    const float* __restrict__ bias, float* __restrict__ out)
{
  const int t = threadIdx.x;
  const int m0 = blockIdx.x * 128;
  const int n0 = blockIdx.y * 64;
  const int w = t >> 6, lane = t & 63;
  const int g = lane >> 4, lc = lane & 15;
  const int wm = w & 1, wn = w >> 1;

  const u16* Arow[4];
#pragma unroll
  for (int mt = 0; mt < 4; ++mt)
    Arow[mt] = AHi + (size_t)(m0 + wm * 64 + mt * 16 + lc) * E_ + 8 * g;
  const u16* Brow[2];
#pragma unroll
  for (int nt = 0; nt < 2; ++nt)
    Brow[nt] = WHi + (size_t)(n0 + wn * 32 + nt * 16 + lc) * E_ + 8 * g;

  f32x4 acc[4][2];
#pragma unroll
  for (int i = 0; i < 4; ++i)
#pragma unroll
    for (int j = 0; j < 2; ++j) acc[i][j] = (f32x4){0.f, 0.f, 0.f, 0.f};

  for (int k0 = 0; k0 < E_; k0 += 32) {
    short8 ah[4], bh[2];
#pragma unroll
    for (int mt = 0; mt < 4; ++mt) ah[mt] = *(const short8*)(Arow[mt] + k0);
#pragma unroll
    for (int nt = 0; nt < 2; ++nt) bh[nt] = *(const short8*)(Brow[nt] + k0);
#pragma unroll
    for (int mt = 0; mt < 4; ++mt)
#pragma unroll
      for (int nt = 0; nt < 2; ++nt)
        acc[mt][nt] = __builtin_amdgcn_mfma_f32_16x16x32_bf16(ah[mt], bh[nt], acc[mt][nt], 0, 0, 0);
  }

  float bs[2];
#pragma unroll
  for (int nt = 0; nt < 2; ++nt) bs[nt] = bias[n0 + wn * 32 + nt * 16 + lc];
#pragma unroll
  for (int nt = 0; nt < 2; ++nt) {
    const int nc = n0 + wn * 32 + nt * 16 + lc;
#pragma unroll
    for (int mt = 0; mt < 4; ++mt) {
#pragma unroll
      for (int r = 0; r < 4; ++r) {
        const int mrow = m0 + wm * 64 + mt * 16 + g * 4 + r;
        out[(size_t)mrow * E_ + nc] = acc[mt][nt][r] + bs[nt];
      }
    }
  }
}

// ---------------------------------------------------------------------------
extern "C" void kernel_launch(void* const* d_in, const int* in_sizes, int n_in,
                              void* d_out, int out_size, void* d_ws, size_t ws_size,
                              hipStream_t stream) {
  const float* q    = (const float*)d_in[0];
  const float* k    = (const float*)d_in[1];
  const float* v    = (const float*)d_in[2];
  const int*   mask = (const int*)d_in[3];
  const float* Wqkv = (const float*)d_in[4];
  const float* bqkv = (const float*)d_in[5];
  const float* Wout = (const float*)d_in[6];
  const float* bout = (const float*)d_in[7];
  float* out = (float*)d_out;

  // Workspace layout (64 MB).
  char* wsb = (char*)d_ws;
  u16* WqkvHi = (u16*)(wsb + 0);          //  6 MB
  u16* WqkvLo = (u16*)(wsb + 6291456);    //  6 MB
  u16* WoutHi = (u16*)(wsb + 12582912);   //  2 MB
  // WoutLo region (2 MB at 14680064) is scratch: split writes it, then the
  // scan kernel reuses the space for opos/nk (stream-ordered, safe).
  int* Opos   = (int*)(wsb + 14680064);   // 16 KB (B*S ints)
  int* Nk     = (int*)(wsb + 14680064 + 16384);  // 8 B
  u16* WoutLo = (u16*)(wsb + 14680064);   // (written then overwritten, unused)
  u16* QpHi   = (u16*)(wsb + 16777216);   //  8 MB
  u16* QpLo   = (u16*)(wsb + 25165824);   //  8 MB
  u16* KpHi   = (u16*)(wsb + 33554432);   //  8 MB
  u16* KpLo   = (u16*)(wsb + 41943040);   //  8 MB
  u16* Vp     = (u16*)(wsb + 50331648);   //  8 MB
  u16* AOHi   = (u16*)(wsb + 58720256);   //  8 MB

  hipLaunchKernelGGL(split_f32_kernel, dim3(3072), dim3(256), 0, stream,
                     Wqkv, WqkvHi, WqkvLo, 786432);
  hipLaunchKernelGGL(split_f32_kernel, dim3(1024), dim3(256), 0, stream,
                     Wout, WoutHi, WoutLo, 262144);
  hipLaunchKernelGGL(mask_scan_kernel, dim3(B_), dim3(256), 0, stream,
                     mask, Opos, Nk);
  // zero V so padded tail columns (>= nk) contribute exact 0 in PV
  hipMemsetAsync(Vp, 0, 8388608, stream);
  hipLaunchKernelGGL(gemm_qkv_kernel, dim3(M_ / 128, 24), dim3(256), 0, stream,
                     q, k, v, WqkvHi, WqkvLo, bqkv, Opos, Nk,
                     QpHi, QpLo, KpHi, KpLo, Vp);
  hipLaunchKernelGGL(attn_mfma_kernel, dim3(S_ / 64, B_ * H_), dim3(256), 0, stream,
                     QpHi, QpLo, KpHi, KpLo, Vp, Nk, AOHi);
  hipLaunchKernelGGL(gemm_out_kernel, dim3(M_ / 128, E_ / 64), dim3(256), 0, stream,
                     AOHi, WoutHi, bout, out);
}

// Round 8
// 295.964 us; speedup vs baseline: 1.3878x; 1.3878x over previous
//
#include <hip/hip_runtime.h>
#include <stdint.h>

// Problem dims (fixed by the reference)
constexpr int B_ = 2, S_ = 2048, E_ = 1024, H_ = 16, D_ = 64;
constexpr int M_ = B_ * S_;              // 4096 rows

typedef unsigned short u16;
typedef __attribute__((ext_vector_type(8))) short short8;
typedef __attribute__((ext_vector_type(4))) float f32x4;

__device__ __forceinline__ u16 f2bf(float f) {
  uint32_t u = __float_as_uint(f);
  return (u16)((u + 0x7FFFu + ((u >> 16) & 1u)) >> 16);  // RNE
}
// truncation split: hi = trunc16(x), lo = trunc16(x - hi). hi+lo ~ x to 2^-17.
__device__ __forceinline__ void tsplit(float x, u16& hi, u16& lo) {
  const uint32_t u = __float_as_uint(x);
  hi = (u16)(u >> 16);
  const float hif = __uint_as_float(u & 0xFFFF0000u);
  lo = (u16)(__float_as_uint(x - hif) >> 16);
}

// Non-draining barrier: waits LDS ops (lgkmcnt) but does NOT drain vmcnt.
__device__ __forceinline__ void block_sync() {
  asm volatile("s_waitcnt lgkmcnt(0)" ::: "memory");
  __builtin_amdgcn_s_barrier();
}

// ---------------------------------------------------------------------------
// Kernel 0: split fp32 -> (hi, lo) bf16 pair, elementwise (weights).
// ---------------------------------------------------------------------------
__global__ __launch_bounds__(256) void split_f32_kernel(
    const float* __restrict__ src, u16* __restrict__ hi, u16* __restrict__ lo, int n4)
{
  const int i = blockIdx.x * 256 + threadIdx.x;
  if (i >= n4) return;
  const float4 x = ((const float4*)src)[i];
  ushort4 h, l;
  tsplit(x.x, h.x, l.x); tsplit(x.y, h.y, l.y);
  tsplit(x.z, h.z, l.z); tsplit(x.w, h.w, l.w);
  ((ushort4*)hi)[i] = h;
  ((ushort4*)lo)[i] = l;
}

// ---------------------------------------------------------------------------
// Kernel 0b: per-batch scan of key mask -> opos (compact slot j -> orig row s)
// and nk[b] (# unmasked keys).
// ---------------------------------------------------------------------------
__global__ __launch_bounds__(256) void mask_scan_kernel(
    const int* __restrict__ mask, int* __restrict__ opos, int* __restrict__ nk)
{
  __shared__ int tmp[256];
  __shared__ int coff;
  const int b = blockIdx.x, t = threadIdx.x;
  for (int c = t; c < S_; c += 256) opos[b * S_ + c] = 0;  // safe default
  if (t == 0) coff = 0;
  __syncthreads();
  for (int c = 0; c < S_; c += 256) {
    const int m = (mask[b * S_ + c + t] != 0) ? 1 : 0;
    int x = m;
    tmp[t] = x;
    __syncthreads();
#pragma unroll
    for (int off = 1; off < 256; off <<= 1) {
      const int v = (t >= off) ? tmp[t - off] : 0;
      __syncthreads();
      x += v;
      tmp[t] = x;
      __syncthreads();
    }
    const int base = coff;
    if (m) opos[b * S_ + base + x - 1] = c + t;  // scatter: slot -> orig row
    __syncthreads();
    if (t == 255) coff = base + x;
    __syncthreads();
  }
  if (t == 0) nk[b] = coff;
}

// ---------------------------------------------------------------------------
// Kernel 1: QKV projection, split-bf16 MFMA + key compaction.
// v8: single-barrier double-buffered LDS pipeline — per 32-k step:
//   barrier -> frag reads (buf p) || stage writes (buf p^1, regs from t-1)
//           || issue loads t+2 -> MFMA.
// 32 barriers total (vs 64); ds_write+load latency hide under MFMA.
// Tile: 128 rows x 64 cols, 4 waves (2m x 2n), wave = 64x32 (acc[4][2]).
// LDS 61.4 KB (2 buffers) -> 2 blocks/CU.
// ---------------------------------------------------------------------------
__global__ __launch_bounds__(256) void gemm_qkv_kernel(
    const float* __restrict__ q, const float* __restrict__ k, const float* __restrict__ v,
    const u16* __restrict__ WHi, const u16* __restrict__ WLo,
    const float* __restrict__ bias,
    const int* __restrict__ Opos, const int* __restrict__ NkArr,
    u16* __restrict__ QpHi, u16* __restrict__ QpLo,
    u16* __restrict__ KpHi, u16* __restrict__ KpLo,
    u16* __restrict__ Vp)
{
  __shared__ __align__(16) short smem[30720];  // 61,440 B: 2 x {Ah,Al,Bh,Bl}

  const int t = threadIdx.x;
  const int m0 = blockIdx.x * 128;
  const int n0g = blockIdx.y * 64;           // global col in [0, 3072)
  const int proj = n0g >> 10;
  const int nloc = n0g & (E_ - 1);
  const bool split = (proj < 2);
  const int bb = m0 >> 11, mloc = m0 & (S_ - 1);
  const int nkb = NkArr[bb];
  if (proj != 0 && mloc >= nkb) return;      // compacted K/V: nothing to do

  const float* A = (proj == 0) ? q : (proj == 1) ? k : v;

  const int w = t >> 6, lane = t & 63;
  const int g = lane >> 4, lc = lane & 15;
  const int wm = w & 1, wn = w >> 1;
  const int sra = t >> 1, sca = (t & 1) * 16; // A staging: 2 thr/row, 16 f32
  const int srb = t >> 2, scb = (t & 3) * 8;  // B staging: 4 thr/row, 8 u16

  // A source row (gathered through opos for K/V)
  int arow;
  if (proj == 0) arow = m0 + sra;
  else arow = bb * S_ + (Opos[bb * S_ + mloc + sra] & (S_ - 1));
  const float* Abp = A + (size_t)arow * E_ + sca;
  const u16* Bhb = WHi + (size_t)(n0g + srb) * E_ + scb;
  const u16* Blb = WLo + (size_t)(n0g + srb) * E_ + scb;

  f32x4 acc[4][2];
#pragma unroll
  for (int i = 0; i < 4; ++i)
#pragma unroll
    for (int j = 0; j < 2; ++j) acc[i][j] = (f32x4){0.f, 0.f, 0.f, 0.f};

  auto loadA = [&](float4* ar, int kk) {
#pragma unroll
    for (int i = 0; i < 4; ++i) ar[i] = *(const float4*)(Abp + kk + 4 * i);
  };
  auto writeAB = [&](const float4* ar, short8 br, short8 cr, int pb) {
    short* Ah = smem + pb * 15360;
    short* Al = Ah + 5120;
    short* Bh = Ah + 10240;
    short* Bl = Ah + 12800;
    ushort hh[16], ll[16];
#pragma unroll
    for (int i = 0; i < 4; ++i) {
      tsplit(ar[i].x, hh[4 * i + 0], ll[4 * i + 0]);
      tsplit(ar[i].y, hh[4 * i + 1], ll[4 * i + 1]);
      tsplit(ar[i].z, hh[4 * i + 2], ll[4 * i + 2]);
      tsplit(ar[i].w, hh[4 * i + 3], ll[4 * i + 3]);
    }
    *(short8*)&Ah[sra * 40 + sca]     = *(const short8*)&hh[0];
    *(short8*)&Ah[sra * 40 + sca + 8] = *(const short8*)&hh[8];
    *(short8*)&Bh[srb * 40 + scb]     = br;
    if (split) {
      *(short8*)&Al[sra * 40 + sca]     = *(const short8*)&ll[0];
      *(short8*)&Al[sra * 40 + sca + 8] = *(const short8*)&ll[8];
      *(short8*)&Bl[srb * 40 + scb]     = cr;
    }
  };

  // prologue: tile 0 -> buf0 (no readers yet); prefetch tile 1 into regs
  float4 ar[4]; short8 br = {}, cr = {};
  loadA(ar, 0);
  br = *(const short8*)(Bhb);
  if (split) cr = *(const short8*)(Blb);
  writeAB(ar, br, cr, 0);
  loadA(ar, 32);
  br = *(const short8*)(Bhb + 32);
  if (split) cr = *(const short8*)(Blb + 32);

  for (int k0 = 0; k0 < E_; k0 += 32) {
    const int p = (k0 >> 5) & 1;
    const short* Ahp = smem + p * 15360;
    const short* Alp = Ahp + 5120;
    const short* Bhp = Ahp + 10240;
    const short* Blp = Ahp + 12800;
    block_sync();                    // buf[p] staged; prev reads of buf[p^1] done
    // frag reads first (in-order lgkm: MFMA waits don't include the writes)
    short8 ah[4], al[4], bh[2], bl[2];
#pragma unroll
    for (int mt = 0; mt < 4; ++mt) {
      const int ro = (wm * 64 + mt * 16 + lc) * 40 + g * 8;
      ah[mt] = *(const short8*)&Ahp[ro];
      if (split) al[mt] = *(const short8*)&Alp[ro];
    }
#pragma unroll
    for (int nt = 0; nt < 2; ++nt) {
      const int ro = (wn * 32 + nt * 16 + lc) * 40 + g * 8;
      bh[nt] = *(const short8*)&Bhp[ro];
      if (split) bl[nt] = *(const short8*)&Blp[ro];
    }
    // stage next tile into the other buffer (overlaps MFMA below)
    if (k0 + 32 < E_) writeAB(ar, br, cr, p ^ 1);
    // issue loads for tile t+2
    if (k0 + 64 < E_) {
      loadA(ar, k0 + 64);
      br = *(const short8*)(Bhb + k0 + 64);
      if (split) cr = *(const short8*)(Blb + k0 + 64);
    }
    // MFMA
#pragma unroll
    for (int mt = 0; mt < 4; ++mt)
#pragma unroll
      for (int nt = 0; nt < 2; ++nt) {
        f32x4 a = acc[mt][nt];
        a = __builtin_amdgcn_mfma_f32_16x16x32_bf16(ah[mt], bh[nt], a, 0, 0, 0);
        if (split) {
          a = __builtin_amdgcn_mfma_f32_16x16x32_bf16(ah[mt], bl[nt], a, 0, 0, 0);
          a = __builtin_amdgcn_mfma_f32_16x16x32_bf16(al[mt], bh[nt], a, 0, 0, 0);
        }
        acc[mt][nt] = a;
      }
  }

  // ---- epilogue ----
  float bs[2];
#pragma unroll
  for (int nt = 0; nt < 2; ++nt) bs[nt] = bias[n0g + wn * 32 + nt * 16 + lc];

  if (proj < 2) {
    // block's 64 n-cols = one head; wave covers d-range wn*32..+31.
    u16* Hi = (proj == 0) ? QpHi : KpHi;
    u16* Lo = (proj == 0) ? QpLo : KpLo;
    const int head = nloc >> 6;
    short* T = smem + w * 2560;               // per-wave [64][40] u16
    const int s = (m0 + wm * 64 + lane) & (S_ - 1);
    const size_t rowb = (((size_t)(bb * H_ + head)) * S_ + s) * D_ + wn * 32;
#pragma unroll
    for (int pass = 0; pass < 2; ++pass) {
      __syncthreads();                        // LDS free / prev pass reads done
#pragma unroll
      for (int nt = 0; nt < 2; ++nt)
#pragma unroll
        for (int mt = 0; mt < 4; ++mt)
#pragma unroll
          for (int r = 0; r < 4; ++r) {
            const float val = acc[mt][nt][r] + bs[nt];
            const uint32_t u = __float_as_uint(val);
            u16 x;
            if (pass == 0) x = (u16)(u >> 16);
            else {
              const float hif = __uint_as_float(u & 0xFFFF0000u);
              x = (u16)(__float_as_uint(val - hif) >> 16);
            }
            T[(mt * 16 + g * 4 + r) * 40 + nt * 16 + lc] = (short)x;
          }
      __syncthreads();
      u16* dst = (pass == 0) ? Hi : Lo;
#pragma unroll
      for (int j = 0; j < 4; ++j)
        *(short8*)&dst[rowb + 8 * j] = *(const short8*)&T[lane * 40 + 8 * j];
    }
  } else {
    // V: [B,H,D,S] layout, compact key columns; predicate j < nk (tail stays 0)
#pragma unroll
    for (int mt = 0; mt < 4; ++mt) {
      const int jb = mloc + wm * 64 + mt * 16 + g * 4;
#pragma unroll
      for (int nt = 0; nt < 2; ++nt) {
        const int nE = nloc + wn * 32 + nt * 16 + lc;
        const int h = nE >> 6, d = nE & 63;
        const size_t rb = (((size_t)(bb * H_ + h)) * D_ + d) * S_;
#pragma unroll
        for (int r = 0; r < 4; ++r) {
          if (jb + r < nkb) Vp[rb + jb + r] = f2bf(acc[mt][nt][r] + bs[nt]);
        }
      }
    }
  }
}

// ---------------------------------------------------------------------------
// Kernel 2: MFMA flash attention. v8: 512-thread blocks (8 waves, 128 q-rows),
// K/V double-buffered, SINGLE barrier per 64-key tile; staging writes and
// t+2 loads overlap the tile's MFMA+softmax. 16 waves/CU maintained
// (2 blocks x 8 waves). LDS 73.7 KB.
// ---------------------------------------------------------------------------
__global__ __launch_bounds__(512, 4) void attn_mfma_kernel(
    const u16* __restrict__ QpHi, const u16* __restrict__ QpLo,
    const u16* __restrict__ KpHi, const u16* __restrict__ KpLo,
    const u16* __restrict__ Vp,
    const int* __restrict__ nkArr,
    u16* __restrict__ AOHi)
{
  // 2 x {Khi [64][72], Klo [64][72], Vt [64][72]} + 8 x P [16][72]
  __shared__ __align__(16) short sm[36864];  // 73,728 B

  const int t = threadIdx.x;
  const int w = t >> 6, lane = t & 63;
  const int g = lane >> 4, lc = lane & 15;
  const int bh = blockIdx.y;
  const int b = bh >> 4, hh = bh & 15;
  const int q0 = blockIdx.x * 128;
  const size_t hb = (size_t)bh * S_ * D_;
  const u16* QgH = QpHi + hb;
  const u16* QgL = QpLo + hb;
  const u16* KgH = KpHi + hb;
  const u16* KgL = KpLo + hb;
  const u16* Vg  = Vp + hb;
  short* Pw = sm + 27648 + w * 1152;

  const int nk = nkArr[b];
  const int kend = ((nk + 63) >> 6) << 6;    // tiles of 64 compacted keys

  // ---- Q A-frags direct from global (lane lc = q-row, k = 8g..8g+7) ----
  short8 qh[2], ql[2];
  {
    const size_t base = (size_t)(q0 + 16 * w + lc) * D_ + 8 * g;
    qh[0] = *(const short8*)&QgH[base];
    qh[1] = *(const short8*)&QgH[base + 32];
    ql[0] = *(const short8*)&QgL[base];
    ql[1] = *(const short8*)&QgL[base + 32];
  }

  // ones column in B (n=0): lanes with lc==0 hold bf16(1.0) for all k
  short8 ones8 = {0, 0, 0, 0, 0, 0, 0, 0};
  if (lc == 0) {
    const short o = (short)0x3F80;
    ones8 = (short8){o, o, o, o, o, o, o, o};
  }

  f32x4 O[4];
  f32x4 Ol = (f32x4){0.f, 0.f, 0.f, 0.f};
#pragma unroll
  for (int dt = 0; dt < 4; ++dt) O[dt] = (f32x4){0.f, 0.f, 0.f, 0.f};
  float mst[4] = {-INFINITY, -INFINITY, -INFINITY, -INFINITY};

  // staging: 512 threads, 8 threads/row, 8 u16 each
  const int srow = t >> 3, sc8 = (t & 7) * 8;

  short8 kr, lr, vr;
  auto loadT = [&](int kt) {
    kr = *(const short8*)&KgH[(kt + srow) * D_ + sc8];
    lr = *(const short8*)&KgL[(kt + srow) * D_ + sc8];
    vr = *(const short8*)&Vg[srow * S_ + kt + sc8];
  };
  auto writeT = [&](int pb) {
    short* base = sm + pb * 13824;
    *(short8*)&base[srow * 72 + sc8]        = kr;  // Khi
    *(short8*)&base[4608 + srow * 72 + sc8] = lr;  // Klo
    *(short8*)&base[9216 + srow * 72 + sc8] = vr;  // Vt
  };

  // prologue: tile 0 -> buf0; prefetch tile 1 regs
  loadT(0);
  writeT(0);
  if (64 < kend) loadT(64);

  for (int kt = 0; kt < kend; kt += 64) {
    const int p = (kt >> 6) & 1;
    const short* Khi = sm + p * 13824;
    const short* Klo = Khi + 4608;
    const short* Vt  = Khi + 9216;
    block_sync();                            // buf[p] staged; prev buf reads done
    // stage next tile (overlaps compute below)
    if (kt + 64 < kend) writeT(p ^ 1);
    if (kt + 128 < kend) loadT(kt + 128);

    // ---- scores: S[16q x 64k] ----
    f32x4 sc[4];
#pragma unroll
    for (int kt16 = 0; kt16 < 4; ++kt16) {
      const int ko = (16 * kt16 + lc) * 72 + 8 * g;
      const short8 kh0 = *(const short8*)&Khi[ko];
      const short8 kh1 = *(const short8*)&Khi[ko + 32];
      const short8 kl0 = *(const short8*)&Klo[ko];
      const short8 kl1 = *(const short8*)&Klo[ko + 32];
      f32x4 a = {0.f, 0.f, 0.f, 0.f};
      a = __builtin_amdgcn_mfma_f32_16x16x32_bf16(qh[0], kh0, a, 0, 0, 0);
      a = __builtin_amdgcn_mfma_f32_16x16x32_bf16(qh[1], kh1, a, 0, 0, 0);
      a = __builtin_amdgcn_mfma_f32_16x16x32_bf16(qh[0], kl0, a, 0, 0, 0);
      a = __builtin_amdgcn_mfma_f32_16x16x32_bf16(qh[1], kl1, a, 0, 0, 0);
      a = __builtin_amdgcn_mfma_f32_16x16x32_bf16(ql[0], kh0, a, 0, 0, 0);
      a = __builtin_amdgcn_mfma_f32_16x16x32_bf16(ql[1], kh1, a, 0, 0, 0);
      sc[kt16] = a;
    }

    // ---- tail masking: compacted cols >= nk are padding (garbage K) ----
    if (kt + 64 > nk) {
#pragma unroll
      for (int kt16 = 0; kt16 < 4; ++kt16) {
        if (kt + 16 * kt16 + lc >= nk) {
          sc[kt16][0] = -1e20f; sc[kt16][1] = -1e20f;
          sc[kt16][2] = -1e20f; sc[kt16][3] = -1e20f;
        }
      }
    }

    // ---- online max + exp (max butterfly only; sum comes from MFMA) ----
    float al[4];
#pragma unroll
    for (int r = 0; r < 4; ++r) {
      float vv = fmaxf(fmaxf(sc[0][r], sc[1][r]), fmaxf(sc[2][r], sc[3][r]));
      vv = fmaxf(vv, __shfl_xor(vv, 1));
      vv = fmaxf(vv, __shfl_xor(vv, 2));
      vv = fmaxf(vv, __shfl_xor(vv, 4));
      vv = fmaxf(vv, __shfl_xor(vv, 8));
      const float mn = fmaxf(mst[r], vv);
      al[r] = __expf(mst[r] - mn);           // first tile: exp(-inf)=0
      mst[r] = mn;
    }
#pragma unroll
    for (int kt16 = 0; kt16 < 4; ++kt16) {
#pragma unroll
      for (int r = 0; r < 4; ++r)
        sc[kt16][r] = __expf(sc[kt16][r] - mst[r]);
    }
    const f32x4 alv = {al[0], al[1], al[2], al[3]};
    O[0] *= alv; O[1] *= alv; O[2] *= alv; O[3] *= alv;
    Ol *= alv;
    // P: C-layout regs -> bf16 LDS (A-layout source for PV)
#pragma unroll
    for (int kt16 = 0; kt16 < 4; ++kt16) {
#pragma unroll
      for (int r = 0; r < 4; ++r)
        Pw[(4 * g + r) * 72 + 16 * kt16 + lc] = (short)f2bf(sc[kt16][r]);
    }

    // ---- PV + denominator via ones ----
    short8 pa[2];
    pa[0] = *(const short8*)&Pw[lc * 72 + 8 * g];
    pa[1] = *(const short8*)&Pw[lc * 72 + 32 + 8 * g];
    Ol = __builtin_amdgcn_mfma_f32_16x16x32_bf16(pa[0], ones8, Ol, 0, 0, 0);
    Ol = __builtin_amdgcn_mfma_f32_16x16x32_bf16(pa[1], ones8, Ol, 0, 0, 0);
#pragma unroll
    for (int dt = 0; dt < 4; ++dt) {
      const int vo = (16 * dt + lc) * 72 + 8 * g;
      const short8 vb0 = *(const short8*)&Vt[vo];
      const short8 vb1 = *(const short8*)&Vt[vo + 32];
      O[dt] = __builtin_amdgcn_mfma_f32_16x16x32_bf16(pa[0], vb0, O[dt], 0, 0, 0);
      O[dt] = __builtin_amdgcn_mfma_f32_16x16x32_bf16(pa[1], vb1, O[dt], 0, 0, 0);
    }
  }

  // ---- epilogue: broadcast denominator (col 0 on lanes lc==0), normalize ----
#pragma unroll
  for (int r = 0; r < 4; ++r) {
    const float lv = __shfl(Ol[r], lane & 48);
    const float lir = 1.0f / lv;
    const int qrow = q0 + 16 * w + 4 * g + r;
    const size_t rowb = (size_t)(b * S_ + qrow) * E_ + hh * 64;
#pragma unroll
    for (int dt = 0; dt < 4; ++dt)
      AOHi[rowb + dt * 16 + lc] = f2bf(O[dt][r] * lir);
  }
}

// ---------------------------------------------------------------------------
// Kernel 3: output projection. v8: 64x64 tiles (grid 1024 blocks), single-
// barrier double-buffered LDS, A & B staged. 4 waves (2m x 2n), wave = 32x32.
// LDS 20.5 KB.
// ---------------------------------------------------------------------------
__global__ __launch_bounds__(256) void gemm_out_kernel(
    const u16* __restrict__ AHi,
    const u16* __restrict__ WHi,
    const float* __restrict__ bias, float* __restrict__ out)
{
  __shared__ __align__(16) short smem[10240];  // 2 x {A[64][40], B[64][40]}

  const int t = threadIdx.x;
  const int m0 = blockIdx.x * 64;
  const int n0 = blockIdx.y * 64;
  const int w = t >> 6, lane = t & 63;
  const int g = lane >> 4, lc = lane & 15;
  const int wm = w & 1, wn = w >> 1;
  const int sr = t >> 2, sc = (t & 3) * 8;     // staging: 4 thr/row, 8 u16

  const u16* Ahb = AHi + (size_t)(m0 + sr) * E_ + sc;
  const u16* Bhb = WHi + (size_t)(n0 + sr) * E_ + sc;

  f32x4 acc[2][2];
#pragma unroll
  for (int i = 0; i < 2; ++i)
#pragma unroll
    for (int j = 0; j < 2; ++j) acc[i][j] = (f32x4){0.f, 0.f, 0.f, 0.f};

  short8 arr, brr;
  arr = *(const short8*)(Ahb);
  brr = *(const short8*)(Bhb);
  *(short8*)&smem[sr * 40 + sc]        = arr;   // buf0 A
  *(short8*)&smem[2560 + sr * 40 + sc] = brr;   // buf0 B
  arr = *(const short8*)(Ahb + 32);
  brr = *(const short8*)(Bhb + 32);

  for (int k0 = 0; k0 < E_; k0 += 32) {
    const int p = (k0 >> 5) & 1;
    const short* Ah = smem + p * 5120;
    const short* Bh = Ah + 2560;
    block_sync();
    short8 ah[2], bh[2];
#pragma unroll
    for (int mt = 0; mt < 2; ++mt)
      ah[mt] = *(const short8*)&Ah[(wm * 32 + mt * 16 + lc) * 40 + g * 8];
#pragma unroll
    for (int nt = 0; nt < 2; ++nt)
      bh[nt] = *(const short8*)&Bh[(wn * 32 + nt * 16 + lc) * 40 + g * 8];
    if (k0 + 32 < E_) {
      short* AhN = smem + (p ^ 1) * 5120;
      *(short8*)&AhN[sr * 40 + sc]        = arr;
      *(short8*)&AhN[2560 + sr * 40 + sc] = brr;
    }
    if (k0 + 64 < E_) {
      arr = *(const short8*)(Ahb + k0 + 64);
      brr = *(const short8*)(Bhb + k0 + 64);
    }
#pragma unroll
    for (int mt = 0; mt < 2; ++mt)
#pragma unroll
      for (int nt = 0; nt < 2; ++nt)
        acc[mt][nt] = __builtin_amdgcn_mfma_f32_16x16x32_bf16(ah[mt], bh[nt], acc[mt][nt], 0, 0, 0);
  }

  float bs[2];
#pragma unroll
  for (int nt = 0; nt < 2; ++nt) bs[nt] = bias[n0 + wn * 32 + nt * 16 + lc];
#pragma unroll
  for (int nt = 0; nt < 2; ++nt) {
    const int nc = n0 + wn * 32 + nt * 16 + lc;
#pragma unroll
    for (int mt = 0; mt < 2; ++mt) {
#pragma unroll
      for (int r = 0; r < 4; ++r) {
        const int mrow = m0 + wm * 32 + mt * 16 + g * 4 + r;
        out[(size_t)mrow * E_ + nc] = acc[mt][nt][r] + bs[nt];
      }
    }
  }
}

// ---------------------------------------------------------------------------
extern "C" void kernel_launch(void* const* d_in, const int* in_sizes, int n_in,
                              void* d_out, int out_size, void* d_ws, size_t ws_size,
                              hipStream_t stream) {
  const float* q    = (const float*)d_in[0];
  const float* k    = (const float*)d_in[1];
  const float* v    = (const float*)d_in[2];
  const int*   mask = (const int*)d_in[3];
  const float* Wqkv = (const float*)d_in[4];
  const float* bqkv = (const float*)d_in[5];
  const float* Wout = (const float*)d_in[6];
  const float* bout = (const float*)d_in[7];
  float* out = (float*)d_out;

  // Workspace layout (64 MB).
  char* wsb = (char*)d_ws;
  u16* WqkvHi = (u16*)(wsb + 0);          //  6 MB
  u16* WqkvLo = (u16*)(wsb + 6291456);    //  6 MB
  u16* WoutHi = (u16*)(wsb + 12582912);   //  2 MB
  // WoutLo region (2 MB at 14680064) is scratch: split writes it, then the
  // scan kernel reuses the space for opos/nk (stream-ordered, safe).
  int* Opos   = (int*)(wsb + 14680064);   // 16 KB (B*S ints)
  int* Nk     = (int*)(wsb + 14680064 + 16384);  // 8 B
  u16* WoutLo = (u16*)(wsb + 14680064);   // (written then overwritten, unused)
  u16* QpHi   = (u16*)(wsb + 16777216);   //  8 MB
  u16* QpLo   = (u16*)(wsb + 25165824);   //  8 MB
  u16* KpHi   = (u16*)(wsb + 33554432);   //  8 MB
  u16* KpLo   = (u16*)(wsb + 41943040);   //  8 MB
  u16* Vp     = (u16*)(wsb + 50331648);   //  8 MB
  u16* AOHi   = (u16*)(wsb + 58720256);   //  8 MB

  hipLaunchKernelGGL(split_f32_kernel, dim3(3072), dim3(256), 0, stream,
                     Wqkv, WqkvHi, WqkvLo, 786432);
  hipLaunchKernelGGL(split_f32_kernel, dim3(1024), dim3(256), 0, stream,
                     Wout, WoutHi, WoutLo, 262144);
  hipLaunchKernelGGL(mask_scan_kernel, dim3(B_), dim3(256), 0, stream,
                     mask, Opos, Nk);
  // zero V so padded tail columns (>= nk) contribute exact 0 in PV
  hipMemsetAsync(Vp, 0, 8388608, stream);
  hipLaunchKernelGGL(gemm_qkv_kernel, dim3(M_ / 128, 48), dim3(256), 0, stream,
                     q, k, v, WqkvHi, WqkvLo, bqkv, Opos, Nk,
                     QpHi, QpLo, KpHi, KpLo, Vp);
  hipLaunchKernelGGL(attn_mfma_kernel, dim3(S_ / 128, B_ * H_), dim3(512), 0, stream,
                     QpHi, QpLo, KpHi, KpLo, Vp, Nk, AOHi);
  hipLaunchKernelGGL(gemm_out_kernel, dim3(M_ / 64, E_ / 64), dim3(256), 0, stream,
                     AOHi, WoutHi, bout, out);
}

// Round 9
// 293.972 us; speedup vs baseline: 1.3972x; 1.0068x over previous
//
#include <hip/hip_runtime.h>
#include <stdint.h>

// Problem dims (fixed by the reference)
constexpr int B_ = 2, S_ = 2048, E_ = 1024, H_ = 16, D_ = 64;
constexpr int M_ = B_ * S_;              // 4096 rows

typedef unsigned short u16;
typedef __attribute__((ext_vector_type(8))) short short8;
typedef __attribute__((ext_vector_type(4))) float f32x4;

__device__ __forceinline__ u16 f2bf(float f) {
  uint32_t u = __float_as_uint(f);
  return (u16)((u + 0x7FFFu + ((u >> 16) & 1u)) >> 16);  // RNE
}
// truncation split: hi = trunc16(x), lo = trunc16(x - hi). hi+lo ~ x to 2^-17.
__device__ __forceinline__ void tsplit(float x, u16& hi, u16& lo) {
  const uint32_t u = __float_as_uint(x);
  hi = (u16)(u >> 16);
  const float hif = __uint_as_float(u & 0xFFFF0000u);
  lo = (u16)(__float_as_uint(x - hif) >> 16);
}

// Non-draining barrier: waits LDS ops (lgkmcnt) but does NOT drain vmcnt.
__device__ __forceinline__ void block_sync() {
  asm volatile("s_waitcnt lgkmcnt(0)" ::: "memory");
  __builtin_amdgcn_s_barrier();
}

// ---------------------------------------------------------------------------
// Kernel 0: split fp32 -> (hi, lo) bf16 pair, elementwise (weights).
// ---------------------------------------------------------------------------
__global__ __launch_bounds__(256) void split_f32_kernel(
    const float* __restrict__ src, u16* __restrict__ hi, u16* __restrict__ lo, int n4)
{
  const int i = blockIdx.x * 256 + threadIdx.x;
  if (i >= n4) return;
  const float4 x = ((const float4*)src)[i];
  ushort4 h, l;
  tsplit(x.x, h.x, l.x); tsplit(x.y, h.y, l.y);
  tsplit(x.z, h.z, l.z); tsplit(x.w, h.w, l.w);
  ((ushort4*)hi)[i] = h;
  ((ushort4*)lo)[i] = l;
}

// ---------------------------------------------------------------------------
// Kernel 0b: per-batch scan of key mask -> opos (compact slot j -> orig row s)
// and nk[b] (# unmasked keys).
// ---------------------------------------------------------------------------
__global__ __launch_bounds__(256) void mask_scan_kernel(
    const int* __restrict__ mask, int* __restrict__ opos, int* __restrict__ nk)
{
  __shared__ int tmp[256];
  __shared__ int coff;
  const int b = blockIdx.x, t = threadIdx.x;
  for (int c = t; c < S_; c += 256) opos[b * S_ + c] = 0;  // safe default
  if (t == 0) coff = 0;
  __syncthreads();
  for (int c = 0; c < S_; c += 256) {
    const int m = (mask[b * S_ + c + t] != 0) ? 1 : 0;
    int x = m;
    tmp[t] = x;
    __syncthreads();
#pragma unroll
    for (int off = 1; off < 256; off <<= 1) {
      const int v = (t >= off) ? tmp[t - off] : 0;
      __syncthreads();
      x += v;
      tmp[t] = x;
      __syncthreads();
    }
    const int base = coff;
    if (m) opos[b * S_ + base + x - 1] = c + t;  // scatter: slot -> orig row
    __syncthreads();
    if (t == 255) coff = base + x;
    __syncthreads();
  }
  if (t == 0) nk[b] = coff;
}

// ---------------------------------------------------------------------------
// Kernel 1: QKV projection, split-bf16 MFMA + key compaction.
// v9: back to the 128x128 tile (round-1 geometry — halves LDS bytes/FLOP,
// the measured bottleneck) + compaction + b128-packed staging writes.
// 4 waves (2m x 2n), wave = 64x64 (acc[4][4]). LDS 40,960 B, single buffer,
// two __syncthreads per 32-k step, distance-1 register prefetch.
// ---------------------------------------------------------------------------
__global__ __launch_bounds__(256) void gemm_qkv_kernel(
    const float* __restrict__ q, const float* __restrict__ k, const float* __restrict__ v,
    const u16* __restrict__ WHi, const u16* __restrict__ WLo,
    const float* __restrict__ bias,
    const int* __restrict__ Opos, const int* __restrict__ NkArr,
    u16* __restrict__ QpHi, u16* __restrict__ QpLo,
    u16* __restrict__ KpHi, u16* __restrict__ KpLo,
    u16* __restrict__ Vp)
{
  __shared__ __align__(16) short smem[20480];  // 40,960 B
  short* Ah = smem;            // [128][40]
  short* Al = smem + 5120;
  short* Bh = smem + 10240;
  short* Bl = smem + 15360;

  const int t = threadIdx.x;
  const int m0 = blockIdx.x * 128;
  const int n0g = blockIdx.y * 128;          // global col in [0, 3072)
  const int proj = n0g >> 10;
  const int nloc = n0g & (E_ - 1);
  const bool split = (proj < 2);
  const int bb = m0 >> 11, mloc = m0 & (S_ - 1);
  const int nkb = NkArr[bb];
  if (proj != 0 && mloc >= nkb) return;      // compacted K/V: nothing to do

  const float* A = (proj == 0) ? q : (proj == 1) ? k : v;

  const int w = t >> 6, lane = t & 63;
  const int g = lane >> 4, lc = lane & 15;
  const int wm = w & 1, wn = w >> 1;
  const int srow = t >> 1, sh = (t & 1) * 16; // staging: 2 threads/row, 16 elems

  // A source row (gathered through opos for K/V)
  int arow;
  if (proj == 0) arow = m0 + srow;
  else arow = bb * S_ + (Opos[bb * S_ + mloc + srow] & (S_ - 1));
  const float* Ab = A + (size_t)arow * E_ + sh;
  const u16* Bhb = WHi + (size_t)(n0g + srow) * E_ + sh;
  const u16* Blb = WLo + (size_t)(n0g + srow) * E_ + sh;

  f32x4 acc[4][4];
#pragma unroll
  for (int i = 0; i < 4; ++i)
#pragma unroll
    for (int j = 0; j < 4; ++j) acc[i][j] = (f32x4){0.f, 0.f, 0.f, 0.f};

  // prefetch registers
  float4 ar[4]; short8 br[2], cr[2];
#pragma unroll
  for (int i = 0; i < 4; ++i) ar[i] = *(const float4*)(Ab + 4 * i);
  br[0] = *(const short8*)(Bhb);     br[1] = *(const short8*)(Bhb + 8);
  if (split) { cr[0] = *(const short8*)(Blb); cr[1] = *(const short8*)(Blb + 8); }

  for (int k0 = 0; k0 < E_; k0 += 32) {
    __syncthreads();                 // previous iteration's frag reads done
    // store staged regs -> LDS (A converted hi/lo, packed b128 writes)
    {
      ushort hh[16], ll[16];
#pragma unroll
      for (int i = 0; i < 4; ++i) {
        tsplit(ar[i].x, hh[4 * i + 0], ll[4 * i + 0]);
        tsplit(ar[i].y, hh[4 * i + 1], ll[4 * i + 1]);
        tsplit(ar[i].z, hh[4 * i + 2], ll[4 * i + 2]);
        tsplit(ar[i].w, hh[4 * i + 3], ll[4 * i + 3]);
      }
      *(short8*)&Ah[srow * 40 + sh]     = *(const short8*)&hh[0];
      *(short8*)&Ah[srow * 40 + sh + 8] = *(const short8*)&hh[8];
      if (split) {
        *(short8*)&Al[srow * 40 + sh]     = *(const short8*)&ll[0];
        *(short8*)&Al[srow * 40 + sh + 8] = *(const short8*)&ll[8];
      }
    }
    *(short8*)&Bh[srow * 40 + sh]     = br[0];
    *(short8*)&Bh[srow * 40 + sh + 8] = br[1];
    if (split) {
      *(short8*)&Bl[srow * 40 + sh]     = cr[0];
      *(short8*)&Bl[srow * 40 + sh + 8] = cr[1];
    }
    __syncthreads();
    // prefetch next K-step (latency hidden behind frag reads + MFMA)
    if (k0 + 32 < E_) {
#pragma unroll
      for (int i = 0; i < 4; ++i) ar[i] = *(const float4*)(Ab + k0 + 32 + 4 * i);
      br[0] = *(const short8*)(Bhb + k0 + 32); br[1] = *(const short8*)(Bhb + k0 + 40);
      if (split) {
        cr[0] = *(const short8*)(Blb + k0 + 32); cr[1] = *(const short8*)(Blb + k0 + 40);
      }
    }

    short8 ah[4], al[4], bh[4], bl[4];
#pragma unroll
    for (int mt = 0; mt < 4; ++mt) {
      const int ro = (wm * 64 + mt * 16 + lc) * 40 + g * 8;
      ah[mt] = *(const short8*)&Ah[ro];
      if (split) al[mt] = *(const short8*)&Al[ro];
    }
#pragma unroll
    for (int nt = 0; nt < 4; ++nt) {
      const int ro = (wn * 64 + nt * 16 + lc) * 40 + g * 8;
      bh[nt] = *(const short8*)&Bh[ro];
      if (split) bl[nt] = *(const short8*)&Bl[ro];
    }
#pragma unroll
    for (int mt = 0; mt < 4; ++mt)
#pragma unroll
      for (int nt = 0; nt < 4; ++nt) {
        f32x4 a = acc[mt][nt];
        a = __builtin_amdgcn_mfma_f32_16x16x32_bf16(ah[mt], bh[nt], a, 0, 0, 0);
        if (split) {
          a = __builtin_amdgcn_mfma_f32_16x16x32_bf16(ah[mt], bl[nt], a, 0, 0, 0);
          a = __builtin_amdgcn_mfma_f32_16x16x32_bf16(al[mt], bh[nt], a, 0, 0, 0);
        }
        acc[mt][nt] = a;
      }
  }

  // ---- epilogue ----
  float bs[4];
#pragma unroll
  for (int nt = 0; nt < 4; ++nt) bs[nt] = bias[n0g + wn * 64 + nt * 16 + lc];

  if (proj < 2) {
    // each wave's 64 n-cols = exactly one head
    u16* Hi = (proj == 0) ? QpHi : KpHi;
    u16* Lo = (proj == 0) ? QpLo : KpLo;
    const int hwave = (nloc + wn * 64) >> 6;
    short* T = smem + w * 4608;               // per-wave [64][72] u16
    // output row: original s for Q; compact slot for K (inputs were gathered)
    const int srow_out = (proj == 0) ? ((m0 + wm * 64 + lane) & (S_ - 1))
                                     : (mloc + wm * 64 + lane);
    const size_t rowb = (((size_t)(bb * H_ + hwave)) * S_ + srow_out) * D_;
#pragma unroll
    for (int pass = 0; pass < 2; ++pass) {
      __syncthreads();                        // LDS free / prev pass reads done
#pragma unroll
      for (int nt = 0; nt < 4; ++nt)
#pragma unroll
        for (int mt = 0; mt < 4; ++mt)
#pragma unroll
          for (int r = 0; r < 4; ++r) {
            const float val = acc[mt][nt][r] + bs[nt];
            const uint32_t u = __float_as_uint(val);
            u16 x;
            if (pass == 0) x = (u16)(u >> 16);
            else {
              const float hif = __uint_as_float(u & 0xFFFF0000u);
              x = (u16)(__float_as_uint(val - hif) >> 16);
            }
            T[(mt * 16 + g * 4 + r) * 72 + nt * 16 + lc] = (short)x;
          }
      __syncthreads();
      u16* dst = (pass == 0) ? Hi : Lo;
#pragma unroll
      for (int j = 0; j < 8; ++j)
        *(short8*)&dst[rowb + 8 * j] = *(const short8*)&T[lane * 72 + 8 * j];
    }
  } else {
    // V: [B,H,D,S] layout, compact key columns; predicate j < nk (tail stays 0)
#pragma unroll
    for (int mt = 0; mt < 4; ++mt) {
      const int jb = mloc + wm * 64 + mt * 16 + g * 4;
#pragma unroll
      for (int nt = 0; nt < 4; ++nt) {
        const int nE = nloc + wn * 64 + nt * 16 + lc;
        const int h = nE >> 6, d = nE & 63;
        const size_t rb = (((size_t)(bb * H_ + h)) * D_ + d) * S_;
#pragma unroll
        for (int r = 0; r < 4; ++r) {
          if (jb + r < nkb) Vp[rb + jb + r] = f2bf(acc[mt][nt][r] + bs[nt]);
        }
      }
    }
  }
}

// ---------------------------------------------------------------------------
// Kernel 2: MFMA flash attention (round-6 version, unchanged).
// ---------------------------------------------------------------------------
__global__ __launch_bounds__(256, 4) void attn_mfma_kernel(
    const u16* __restrict__ QpHi, const u16* __restrict__ QpLo,
    const u16* __restrict__ KpHi, const u16* __restrict__ KpLo,
    const u16* __restrict__ Vp,
    const int* __restrict__ nkArr,
    u16* __restrict__ AOHi)
{
  __shared__ __align__(16) short sm[18432];  // 36,864 B
  short* Khi = sm;                           // [64][72]
  short* Klo = sm + 4608;                    // [64][72]
  short* Vt  = sm + 9216;                    // [64][72] (d-major)
  short* Pb  = sm + 13824;                   // 4 waves x [16][72]

  const int t = threadIdx.x;
  const int w = t >> 6, lane = t & 63;
  const int g = lane >> 4, lc = lane & 15;
  const int bh = blockIdx.y;
  const int b = bh >> 4, hh = bh & 15;
  const int q0 = blockIdx.x * 64;
  const size_t hb = (size_t)bh * S_ * D_;
  const u16* QgH = QpHi + hb;
  const u16* QgL = QpLo + hb;
  const u16* KgH = KpHi + hb;
  const u16* KgL = KpLo + hb;
  const u16* Vg  = Vp + hb;
  short* Pw = Pb + w * 1152;

  const int nk = nkArr[b];
  const int kend = ((nk + 63) >> 6) << 6;    // tiles of 64 compacted keys

  // ---- Q A-frags direct from global (lane lc = q-row, k = 8g..8g+7) ----
  short8 qh[2], ql[2];
  {
    const size_t base = (size_t)(q0 + 16 * w + lc) * D_ + 8 * g;
    qh[0] = *(const short8*)&QgH[base];
    qh[1] = *(const short8*)&QgH[base + 32];
    ql[0] = *(const short8*)&QgL[base];
    ql[1] = *(const short8*)&QgL[base + 32];
  }

  // ones column in B (n=0): lanes with lc==0 hold bf16(1.0) for all k
  short8 ones8 = {0, 0, 0, 0, 0, 0, 0, 0};
  if (lc == 0) {
    const short o = (short)0x3F80;
    ones8 = (short8){o, o, o, o, o, o, o, o};
  }

  f32x4 O[4];
  f32x4 Ol = (f32x4){0.f, 0.f, 0.f, 0.f};
#pragma unroll
  for (int dt = 0; dt < 4; ++dt) O[dt] = (f32x4){0.f, 0.f, 0.f, 0.f};
  float mst[4] = {-INFINITY, -INFINITY, -INFINITY, -INFINITY};

  const int srow = t >> 2, sc16 = (t & 3) * 16;   // staging: 4 threads/row

  // staging prefetch registers (K hi/lo, V)
  short8 kr[2], lr[2], vr[2];
  kr[0] = *(const short8*)&KgH[srow * D_ + sc16];
  kr[1] = *(const short8*)&KgH[srow * D_ + sc16 + 8];
  lr[0] = *(const short8*)&KgL[srow * D_ + sc16];
  lr[1] = *(const short8*)&KgL[srow * D_ + sc16 + 8];
  vr[0] = *(const short8*)&Vg[srow * S_ + sc16];
  vr[1] = *(const short8*)&Vg[srow * S_ + sc16 + 8];

  for (int kt = 0; kt < kend; kt += 64) {
    block_sync();                            // previous tile fully consumed
    *(short8*)&Khi[srow * 72 + sc16]     = kr[0];
    *(short8*)&Khi[srow * 72 + sc16 + 8] = kr[1];
    *(short8*)&Klo[srow * 72 + sc16]     = lr[0];
    *(short8*)&Klo[srow * 72 + sc16 + 8] = lr[1];
    *(short8*)&Vt[srow * 72 + sc16]      = vr[0];
    *(short8*)&Vt[srow * 72 + sc16 + 8]  = vr[1];
    block_sync();
    if (kt + 64 < kend) {                    // prefetch next tile
      const int kn = kt + 64;
      kr[0] = *(const short8*)&KgH[(kn + srow) * D_ + sc16];
      kr[1] = *(const short8*)&KgH[(kn + srow) * D_ + sc16 + 8];
      lr[0] = *(const short8*)&KgL[(kn + srow) * D_ + sc16];
      lr[1] = *(const short8*)&KgL[(kn + srow) * D_ + sc16 + 8];
      vr[0] = *(const short8*)&Vg[srow * S_ + kn + sc16];
      vr[1] = *(const short8*)&Vg[srow * S_ + kn + sc16 + 8];
    }

    // ---- scores: S[16q x 64k] ----
    f32x4 sc[4];
#pragma unroll
    for (int kt16 = 0; kt16 < 4; ++kt16) {
      const int ko = (16 * kt16 + lc) * 72 + 8 * g;
      const short8 kh0 = *(const short8*)&Khi[ko];
      const short8 kh1 = *(const short8*)&Khi[ko + 32];
      const short8 kl0 = *(const short8*)&Klo[ko];
      const short8 kl1 = *(const short8*)&Klo[ko + 32];
      f32x4 a = {0.f, 0.f, 0.f, 0.f};
      a = __builtin_amdgcn_mfma_f32_16x16x32_bf16(qh[0], kh0, a, 0, 0, 0);
      a = __builtin_amdgcn_mfma_f32_16x16x32_bf16(qh[1], kh1, a, 0, 0, 0);
      a = __builtin_amdgcn_mfma_f32_16x16x32_bf16(qh[0], kl0, a, 0, 0, 0);
      a = __builtin_amdgcn_mfma_f32_16x16x32_bf16(qh[1], kl1, a, 0, 0, 0);
      a = __builtin_amdgcn_mfma_f32_16x16x32_bf16(ql[0], kh0, a, 0, 0, 0);
      a = __builtin_amdgcn_mfma_f32_16x16x32_bf16(ql[1], kh1, a, 0, 0, 0);
      sc[kt16] = a;
    }

    // ---- tail masking: compacted cols >= nk are padding (garbage K) ----
    if (kt + 64 > nk) {
#pragma unroll
      for (int kt16 = 0; kt16 < 4; ++kt16) {
        if (kt + 16 * kt16 + lc >= nk) {
          sc[kt16][0] = -1e20f; sc[kt16][1] = -1e20f;
          sc[kt16][2] = -1e20f; sc[kt16][3] = -1e20f;
        }
      }
    }

    // ---- online max + exp (max butterfly only; sum comes from MFMA) ----
    float al[4];
#pragma unroll
    for (int r = 0; r < 4; ++r) {
      float vv = fmaxf(fmaxf(sc[0][r], sc[1][r]), fmaxf(sc[2][r], sc[3][r]));
      vv = fmaxf(vv, __shfl_xor(vv, 1));
      vv = fmaxf(vv, __shfl_xor(vv, 2));
      vv = fmaxf(vv, __shfl_xor(vv, 4));
      vv = fmaxf(vv, __shfl_xor(vv, 8));
      const float mn = fmaxf(mst[r], vv);
      al[r] = __expf(mst[r] - mn);           // first tile: exp(-inf)=0
      mst[r] = mn;
    }
#pragma unroll
    for (int kt16 = 0; kt16 < 4; ++kt16) {
#pragma unroll
      for (int r = 0; r < 4; ++r)
        sc[kt16][r] = __expf(sc[kt16][r] - mst[r]);
    }
    const f32x4 alv = {al[0], al[1], al[2], al[3]};
    O[0] *= alv; O[1] *= alv; O[2] *= alv; O[3] *= alv;
    Ol *= alv;
    // P: C-layout regs -> bf16 LDS (A-layout source for PV)
#pragma unroll
    for (int kt16 = 0; kt16 < 4; ++kt16) {
#pragma unroll
      for (int r = 0; r < 4; ++r)
        Pw[(4 * g + r) * 72 + 16 * kt16 + lc] = (short)f2bf(sc[kt16][r]);
    }

    // ---- PV + denominator via ones ----
    short8 pa[2];
    pa[0] = *(const short8*)&Pw[lc * 72 + 8 * g];
    pa[1] = *(const short8*)&Pw[lc * 72 + 32 + 8 * g];
    Ol = __builtin_amdgcn_mfma_f32_16x16x32_bf16(pa[0], ones8, Ol, 0, 0, 0);
    Ol = __builtin_amdgcn_mfma_f32_16x16x32_bf16(pa[1], ones8, Ol, 0, 0, 0);
#pragma unroll
    for (int dt = 0; dt < 4; ++dt) {
      const int vo = (16 * dt + lc) * 72 + 8 * g;
      const short8 vb0 = *(const short8*)&Vt[vo];
      const short8 vb1 = *(const short8*)&Vt[vo + 32];
      O[dt] = __builtin_amdgcn_mfma_f32_16x16x32_bf16(pa[0], vb0, O[dt], 0, 0, 0);
      O[dt] = __builtin_amdgcn_mfma_f32_16x16x32_bf16(pa[1], vb1, O[dt], 0, 0, 0);
    }
  }

  // ---- epilogue: broadcast denominator (col 0 on lanes lc==0), normalize ----
#pragma unroll
  for (int r = 0; r < 4; ++r) {
    const float lv = __shfl(Ol[r], lane & 48);
    const float lir = 1.0f / lv;
    const int qrow = q0 + 16 * w + 4 * g + r;
    const size_t rowb = (size_t)(b * S_ + qrow) * E_ + hh * 64;
#pragma unroll
    for (int dt = 0; dt < 4; ++dt)
      AOHi[rowb + dt * 16 + lc] = f2bf(O[dt][r] * lir);
  }
}

// ---------------------------------------------------------------------------
// Kernel 3: output projection (round-6 version, unchanged).
// 64x64 tiles (grid 1024 blocks), distance-2 register prefetch, A & B
// LDS-staged, non-draining barriers. 4 waves (2m x 2n), wave = 32x32.
// ---------------------------------------------------------------------------
__global__ __launch_bounds__(256) void gemm_out_kernel(
    const u16* __restrict__ AHi,
    const u16* __restrict__ WHi,
    const float* __restrict__ bias, float* __restrict__ out)
{
  __shared__ __align__(16) short smem[5120];   // A[64][40] + B[64][40]
  short* Ah = smem;
  short* Bh = smem + 2560;

  const int t = threadIdx.x;
  const int m0 = blockIdx.x * 64;
  const int n0 = blockIdx.y * 64;
  const int w = t >> 6, lane = t & 63;
  const int g = lane >> 4, lc = lane & 15;
  const int wm = w & 1, wn = w >> 1;
  const int sr = t >> 2, sc = (t & 3) * 8;     // staging: 4 thr/row, 8 u16

  const u16* Ahb = AHi + (size_t)(m0 + sr) * E_ + sc;
  const u16* Bhb = WHi + (size_t)(n0 + sr) * E_ + sc;

  f32x4 acc[2][2];
#pragma unroll
  for (int i = 0; i < 2; ++i)
#pragma unroll
    for (int j = 0; j < 2; ++j) acc[i][j] = (f32x4){0.f, 0.f, 0.f, 0.f};

  short8 arP[2], brP[2];
  arP[0] = *(const short8*)(Ahb);
  arP[1] = *(const short8*)(Ahb + 32);
  brP[0] = *(const short8*)(Bhb);
  brP[1] = *(const short8*)(Bhb + 32);

#pragma unroll 2
  for (int k0 = 0; k0 < E_; k0 += 32) {
    const int p = (k0 >> 5) & 1;
    block_sync();
    *(short8*)&Ah[sr * 40 + sc] = arP[p];
    *(short8*)&Bh[sr * 40 + sc] = brP[p];
    block_sync();
    {
      const int kk = (k0 + 64) & (E_ - 1);
      arP[p] = *(const short8*)(Ahb + kk);
      brP[p] = *(const short8*)(Bhb + kk);
    }

    short8 ah[2], bh[2];
#pragma unroll
    for (int mt = 0; mt < 2; ++mt)
      ah[mt] = *(const short8*)&Ah[(wm * 32 + mt * 16 + lc) * 40 + g * 8];
#pragma unroll
    for (int nt = 0; nt < 2; ++nt)
      bh[nt] = *(const short8*)&Bh[(wn * 32 + nt * 16 + lc) * 40 + g * 8];
#pragma unroll
    for (int mt = 0; mt < 2; ++mt)
#pragma unroll
      for (int nt = 0; nt < 2; ++nt)
        acc[mt][nt] = __builtin_amdgcn_mfma_f32_16x16x32_bf16(ah[mt], bh[nt], acc[mt][nt], 0, 0, 0);
  }

  float bs[2];
#pragma unroll
  for (int nt = 0; nt < 2; ++nt) bs[nt] = bias[n0 + wn * 32 + nt * 16 + lc];
#pragma unroll
  for (int nt = 0; nt < 2; ++nt) {
    const int nc = n0 + wn * 32 + nt * 16 + lc;
#pragma unroll
    for (int mt = 0; mt < 2; ++mt) {
#pragma unroll
      for (int r = 0; r < 4; ++r) {
        const int mrow = m0 + wm * 32 + mt * 16 + g * 4 + r;
        out[(size_t)mrow * E_ + nc] = acc[mt][nt][r] + bs[nt];
      }
    }
  }
}

// ---------------------------------------------------------------------------
extern "C" void kernel_launch(void* const* d_in, const int* in_sizes, int n_in,
                              void* d_out, int out_size, void* d_ws, size_t ws_size,
                              hipStream_t stream) {
  const float* q    = (const float*)d_in[0];
  const float* k    = (const float*)d_in[1];
  const float* v    = (const float*)d_in[2];
  const int*   mask = (const int*)d_in[3];
  const float* Wqkv = (const float*)d_in[4];
  const float* bqkv = (const float*)d_in[5];
  const float* Wout = (const float*)d_in[6];
  const float* bout = (const float*)d_in[7];
  float* out = (float*)d_out;

  // Workspace layout (64 MB).
  char* wsb = (char*)d_ws;
  u16* WqkvHi = (u16*)(wsb + 0);          //  6 MB
  u16* WqkvLo = (u16*)(wsb + 6291456);    //  6 MB
  u16* WoutHi = (u16*)(wsb + 12582912);   //  2 MB
  // WoutLo region (2 MB at 14680064) is scratch: split writes it, then the
  // scan kernel reuses the space for opos/nk (stream-ordered, safe).
  int* Opos   = (int*)(wsb + 14680064);   // 16 KB (B*S ints)
  int* Nk     = (int*)(wsb + 14680064 + 16384);  // 8 B
  u16* WoutLo = (u16*)(wsb + 14680064);   // (written then overwritten, unused)
  u16* QpHi   = (u16*)(wsb + 16777216);   //  8 MB
  u16* QpLo   = (u16*)(wsb + 25165824);   //  8 MB
  u16* KpHi   = (u16*)(wsb + 33554432);   //  8 MB
  u16* KpLo   = (u16*)(wsb + 41943040);   //  8 MB
  u16* Vp     = (u16*)(wsb + 50331648);   //  8 MB
  u16* AOHi   = (u16*)(wsb + 58720256);   //  8 MB

  hipLaunchKernelGGL(split_f32_kernel, dim3(3072), dim3(256), 0, stream,
                     Wqkv, WqkvHi, WqkvLo, 786432);
  hipLaunchKernelGGL(split_f32_kernel, dim3(1024), dim3(256), 0, stream,
                     Wout, WoutHi, WoutLo, 262144);
  hipLaunchKernelGGL(mask_scan_kernel, dim3(B_), dim3(256), 0, stream,
                     mask, Opos, Nk);
  // zero V so padded tail columns (>= nk) contribute exact 0 in PV
  hipMemsetAsync(Vp, 0, 8388608, stream);
  hipLaunchKernelGGL(gemm_qkv_kernel, dim3(M_ / 128, 24), dim3(256), 0, stream,
                     q, k, v, WqkvHi, WqkvLo, bqkv, Opos, Nk,
                     QpHi, QpLo, KpHi, KpLo, Vp);
  hipLaunchKernelGGL(attn_mfma_kernel, dim3(S_ / 64, B_ * H_), dim3(256), 0, stream,
                     QpHi, QpLo, KpHi, KpLo, Vp, Nk, AOHi);
  hipLaunchKernelGGL(gemm_out_kernel, dim3(M_ / 64, E_ / 64), dim3(256), 0, stream,
                     AOHi, WoutHi, bout, out);
}

// Round 10
// 266.442 us; speedup vs baseline: 1.5415x; 1.1033x over previous
//
#include <hip/hip_runtime.h>
#include <stdint.h>

// Problem dims (fixed by the reference)
constexpr int B_ = 2, S_ = 2048, E_ = 1024, H_ = 16, D_ = 64;
constexpr int M_ = B_ * S_;              // 4096 rows

typedef unsigned short u16;
typedef __attribute__((ext_vector_type(8))) short short8;
typedef __attribute__((ext_vector_type(4))) float f32x4;

__device__ __forceinline__ u16 f2bf(float f) {
  uint32_t u = __float_as_uint(f);
  return (u16)((u + 0x7FFFu + ((u >> 16) & 1u)) >> 16);  // RNE
}
// truncation split: hi = trunc16(x), lo = trunc16(x - hi). hi+lo ~ x to 2^-17.
__device__ __forceinline__ void tsplit(float x, u16& hi, u16& lo) {
  const uint32_t u = __float_as_uint(x);
  hi = (u16)(u >> 16);
  const float hif = __uint_as_float(u & 0xFFFF0000u);
  lo = (u16)(__float_as_uint(x - hif) >> 16);
}

// Non-draining barrier (attn only): waits LDS ops but not vmcnt.
__device__ __forceinline__ void block_sync() {
  asm volatile("s_waitcnt lgkmcnt(0)" ::: "memory");
  __builtin_amdgcn_s_barrier();
}

// async global->LDS, 16 B per lane; LDS dest = wave-uniform base + lane*16.
typedef const __attribute__((address_space(1))) unsigned int GU32;
typedef __attribute__((address_space(3))) unsigned int LU32;
__device__ __forceinline__ void gload16(const void* g, void* l) {
  __builtin_amdgcn_global_load_lds((GU32*)g, (LU32*)l, 16, 0, 0);
}

// ---------------------------------------------------------------------------
// Kernel 0: split fp32 -> (hi, lo) bf16 pair, elementwise (weights).
// ---------------------------------------------------------------------------
__global__ __launch_bounds__(256) void split_f32_kernel(
    const float* __restrict__ src, u16* __restrict__ hi, u16* __restrict__ lo, int n4)
{
  const int i = blockIdx.x * 256 + threadIdx.x;
  if (i >= n4) return;
  const float4 x = ((const float4*)src)[i];
  ushort4 h, l;
  tsplit(x.x, h.x, l.x); tsplit(x.y, h.y, l.y);
  tsplit(x.z, h.z, l.z); tsplit(x.w, h.w, l.w);
  ((ushort4*)hi)[i] = h;
  ((ushort4*)lo)[i] = l;
}

// ---------------------------------------------------------------------------
// Kernel 0b: per-batch scan of key mask -> opos (compact slot j -> orig row s)
// and nk[b] (# unmasked keys).
// ---------------------------------------------------------------------------
__global__ __launch_bounds__(256) void mask_scan_kernel(
    const int* __restrict__ mask, int* __restrict__ opos, int* __restrict__ nk)
{
  __shared__ int tmp[256];
  __shared__ int coff;
  const int b = blockIdx.x, t = threadIdx.x;
  for (int c = t; c < S_; c += 256) opos[b * S_ + c] = 0;  // safe default
  if (t == 0) coff = 0;
  __syncthreads();
  for (int c = 0; c < S_; c += 256) {
    const int m = (mask[b * S_ + c + t] != 0) ? 1 : 0;
    int x = m;
    tmp[t] = x;
    __syncthreads();
#pragma unroll
    for (int off = 1; off < 256; off <<= 1) {
      const int v = (t >= off) ? tmp[t - off] : 0;
      __syncthreads();
      x += v;
      tmp[t] = x;
      __syncthreads();
    }
    const int base = coff;
    if (m) opos[b * S_ + base + x - 1] = c + t;  // scatter: slot -> orig row
    __syncthreads();
    if (t == 255) coff = base + x;
    __syncthreads();
  }
  if (t == 0) nk[b] = coff;
}

// ---------------------------------------------------------------------------
// Kernel 1: QKV projection, split-bf16 MFMA + key compaction.
// v10 = v9 (128x128 tile) with B staged via global_load_lds width=16
// (the m93->m97 ladder step): B tiles unpadded [128][32] with XOR swizzle
// chunk^=( row>>1)&3 (2-way banks = free), source pre-swizzled, LDS linear.
// A stays reg-staged (fp32 -> tsplit -> ds_write, padded [128][40]).
// LDS 36,864 B -> 4 blocks/CU.
// ---------------------------------------------------------------------------
__global__ __launch_bounds__(256) void gemm_qkv_kernel(
    const float* __restrict__ q, const float* __restrict__ k, const float* __restrict__ v,
    const u16* __restrict__ WHi, const u16* __restrict__ WLo,
    const float* __restrict__ bias,
    const int* __restrict__ Opos, const int* __restrict__ NkArr,
    u16* __restrict__ QpHi, u16* __restrict__ QpLo,
    u16* __restrict__ KpHi, u16* __restrict__ KpLo,
    u16* __restrict__ Vp)
{
  __shared__ __align__(16) short smem[18432];  // 36,864 B
  short* Ah = smem;            // [128][40] hi
  short* Al = smem + 5120;     // [128][40] lo
  short* Bh = smem + 10240;    // [128][32] hi (swizzled)
  short* Bl = smem + 14336;    // [128][32] lo (swizzled)

  const int t = threadIdx.x;
  const int m0 = blockIdx.x * 128;
  const int n0g = blockIdx.y * 128;          // global col in [0, 3072)
  const int proj = n0g >> 10;
  const int nloc = n0g & (E_ - 1);
  const bool split = (proj < 2);
  const int bb = m0 >> 11, mloc = m0 & (S_ - 1);
  const int nkb = NkArr[bb];
  if (proj != 0 && mloc >= nkb) return;      // compacted K/V: nothing to do

  const float* A = (proj == 0) ? q : (proj == 1) ? k : v;

  const int w = t >> 6, lane = t & 63;
  const int g = lane >> 4, lc = lane & 15;
  const int wm = w & 1, wn = w >> 1;
  const int sra = t >> 1, sca = (t & 1) * 16; // A staging: 2 thr/row, 16 f32

  // A source row (gathered through opos for K/V)
  int arow;
  if (proj == 0) arow = m0 + sra;
  else arow = bb * S_ + (Opos[bb * S_ + mloc + sra] & (S_ - 1));
  const float* Ab = A + (size_t)arow * E_ + sca;

  f32x4 acc[4][4];
#pragma unroll
  for (int i = 0; i < 4; ++i)
#pragma unroll
    for (int j = 0; j < 4; ++j) acc[i][j] = (f32x4){0.f, 0.f, 0.f, 0.f};

  auto loadA = [&](float4* a, int kk) {
#pragma unroll
    for (int i = 0; i < 4; ++i) a[i] = *(const float4*)(Ab + kk + 4 * i);
  };
  auto writeA = [&](const float4* a) {
    ushort hh[16], ll[16];
#pragma unroll
    for (int i = 0; i < 4; ++i) {
      tsplit(a[i].x, hh[4 * i + 0], ll[4 * i + 0]);
      tsplit(a[i].y, hh[4 * i + 1], ll[4 * i + 1]);
      tsplit(a[i].z, hh[4 * i + 2], ll[4 * i + 2]);
      tsplit(a[i].w, hh[4 * i + 3], ll[4 * i + 3]);
    }
    *(short8*)&Ah[sra * 40 + sca]     = *(const short8*)&hh[0];
    *(short8*)&Ah[sra * 40 + sca + 8] = *(const short8*)&hh[8];
    if (split) {
      *(short8*)&Al[sra * 40 + sca]     = *(const short8*)&ll[0];
      *(short8*)&Al[sra * 40 + sca + 8] = *(const short8*)&ll[8];
    }
  };
  // B: 512 chunks of 16B per tile; wave w stages chunks [(w*2+i)*64 + lane].
  // Physical chunk p holds logical chunk (p&3)^((row>>1)&3) of row p>>2.
  auto gloadB = [&](int k0) {
#pragma unroll
    for (int i = 0; i < 2; ++i) {
      const int c = (w * 2 + i) * 64 + lane;
      const int row = c >> 2;
      const int sub = (c & 3) ^ ((row >> 1) & 3);
      const size_t go = (size_t)(n0g + row) * E_ + k0 + sub * 8;
      gload16(WHi + go, (char*)Bh + (w * 2 + i) * 1024);
      if (split) gload16(WLo + go, (char*)Bl + (w * 2 + i) * 1024);
    }
  };

  // prologue: A regs for step 0
  float4 ar[4];
  loadA(ar, 0);

  for (int k0 = 0; k0 < E_; k0 += 32) {
    __syncthreads();                 // prev frag reads done -> LDS free
    writeA(ar);                      // A: tsplit + ds_write
    gloadB(k0);                      // B: async global->LDS
    __syncthreads();                 // A visible (lgkm); B arrived (vmcnt drain)
    if (k0 + 32 < E_) loadA(ar, k0 + 32);  // prefetch next A regs

    short8 ah[4], al[4], bh[4], bl[4];
#pragma unroll
    for (int mt = 0; mt < 4; ++mt) {
      const int ro = (wm * 64 + mt * 16 + lc) * 40 + g * 8;
      ah[mt] = *(const short8*)&Ah[ro];
      if (split) al[mt] = *(const short8*)&Al[ro];
    }
#pragma unroll
    for (int nt = 0; nt < 4; ++nt) {
      const int row = wn * 64 + nt * 16 + lc;
      const int ro = row * 32 + ((g ^ ((row >> 1) & 3)) * 8);
      bh[nt] = *(const short8*)&Bh[ro];
      if (split) bl[nt] = *(const short8*)&Bl[ro];
    }
#pragma unroll
    for (int mt = 0; mt < 4; ++mt)
#pragma unroll
      for (int nt = 0; nt < 4; ++nt) {
        f32x4 a = acc[mt][nt];
        a = __builtin_amdgcn_mfma_f32_16x16x32_bf16(ah[mt], bh[nt], a, 0, 0, 0);
        if (split) {
          a = __builtin_amdgcn_mfma_f32_16x16x32_bf16(ah[mt], bl[nt], a, 0, 0, 0);
          a = __builtin_amdgcn_mfma_f32_16x16x32_bf16(al[mt], bh[nt], a, 0, 0, 0);
        }
        acc[mt][nt] = a;
      }
  }

  // ---- epilogue ----
  float bs[4];
#pragma unroll
  for (int nt = 0; nt < 4; ++nt) bs[nt] = bias[n0g + wn * 64 + nt * 16 + lc];

  if (proj < 2) {
    // each wave's 64 n-cols = exactly one head
    u16* Hi = (proj == 0) ? QpHi : KpHi;
    u16* Lo = (proj == 0) ? QpLo : KpLo;
    const int hwave = (nloc + wn * 64) >> 6;
    short* T = smem + w * 4608;               // per-wave [64][72] u16
    const int srow_out = (proj == 0) ? ((m0 + wm * 64 + lane) & (S_ - 1))
                                     : (mloc + wm * 64 + lane);
    const size_t rowb = (((size_t)(bb * H_ + hwave)) * S_ + srow_out) * D_;
#pragma unroll
    for (int pass = 0; pass < 2; ++pass) {
      __syncthreads();                        // LDS free / prev pass reads done
#pragma unroll
      for (int nt = 0; nt < 4; ++nt)
#pragma unroll
        for (int mt = 0; mt < 4; ++mt)
#pragma unroll
          for (int r = 0; r < 4; ++r) {
            const float val = acc[mt][nt][r] + bs[nt];
            const uint32_t u = __float_as_uint(val);
            u16 x;
            if (pass == 0) x = (u16)(u >> 16);
            else {
              const float hif = __uint_as_float(u & 0xFFFF0000u);
              x = (u16)(__float_as_uint(val - hif) >> 16);
            }
            T[(mt * 16 + g * 4 + r) * 72 + nt * 16 + lc] = (short)x;
          }
      __syncthreads();
      u16* dst = (pass == 0) ? Hi : Lo;
#pragma unroll
      for (int j = 0; j < 8; ++j)
        *(short8*)&dst[rowb + 8 * j] = *(const short8*)&T[lane * 72 + 8 * j];
    }
  } else {
    // V: [B,H,D,S] layout, compact key columns; predicate j < nk (tail stays 0)
#pragma unroll
    for (int mt = 0; mt < 4; ++mt) {
      const int jb = mloc + wm * 64 + mt * 16 + g * 4;
#pragma unroll
      for (int nt = 0; nt < 4; ++nt) {
        const int nE = nloc + wn * 64 + nt * 16 + lc;
        const int h = nE >> 6, d = nE & 63;
        const size_t rb = (((size_t)(bb * H_ + h)) * D_ + d) * S_;
#pragma unroll
        for (int r = 0; r < 4; ++r) {
          if (jb + r < nkb) Vp[rb + jb + r] = f2bf(acc[mt][nt][r] + bs[nt]);
        }
      }
    }
  }
}

// ---------------------------------------------------------------------------
// Kernel 2: MFMA flash attention (round-6 version, unchanged).
// ---------------------------------------------------------------------------
__global__ __launch_bounds__(256, 4) void attn_mfma_kernel(
    const u16* __restrict__ QpHi, const u16* __restrict__ QpLo,
    const u16* __restrict__ KpHi, const u16* __restrict__ KpLo,
    const u16* __restrict__ Vp,
    const int* __restrict__ nkArr,
    u16* __restrict__ AOHi)
{
  __shared__ __align__(16) short sm[18432];  // 36,864 B
  short* Khi = sm;                           // [64][72]
  short* Klo = sm + 4608;                    // [64][72]
  short* Vt  = sm + 9216;                    // [64][72] (d-major)
  short* Pb  = sm + 13824;                   // 4 waves x [16][72]

  const int t = threadIdx.x;
  const int w = t >> 6, lane = t & 63;
  const int g = lane >> 4, lc = lane & 15;
  const int bh = blockIdx.y;
  const int b = bh >> 4, hh = bh & 15;
  const int q0 = blockIdx.x * 64;
  const size_t hb = (size_t)bh * S_ * D_;
  const u16* QgH = QpHi + hb;
  const u16* QgL = QpLo + hb;
  const u16* KgH = KpHi + hb;
  const u16* KgL = KpLo + hb;
  const u16* Vg  = Vp + hb;
  short* Pw = Pb + w * 1152;

  const int nk = nkArr[b];
  const int kend = ((nk + 63) >> 6) << 6;    // tiles of 64 compacted keys

  // ---- Q A-frags direct from global (lane lc = q-row, k = 8g..8g+7) ----
  short8 qh[2], ql[2];
  {
    const size_t base = (size_t)(q0 + 16 * w + lc) * D_ + 8 * g;
    qh[0] = *(const short8*)&QgH[base];
    qh[1] = *(const short8*)&QgH[base + 32];
    ql[0] = *(const short8*)&QgL[base];
    ql[1] = *(const short8*)&QgL[base + 32];
  }

  // ones column in B (n=0): lanes with lc==0 hold bf16(1.0) for all k
  short8 ones8 = {0, 0, 0, 0, 0, 0, 0, 0};
  if (lc == 0) {
    const short o = (short)0x3F80;
    ones8 = (short8){o, o, o, o, o, o, o, o};
  }

  f32x4 O[4];
  f32x4 Ol = (f32x4){0.f, 0.f, 0.f, 0.f};
#pragma unroll
  for (int dt = 0; dt < 4; ++dt) O[dt] = (f32x4){0.f, 0.f, 0.f, 0.f};
  float mst[4] = {-INFINITY, -INFINITY, -INFINITY, -INFINITY};

  const int srow = t >> 2, sc16 = (t & 3) * 16;   // staging: 4 threads/row

  // staging prefetch registers (K hi/lo, V)
  short8 kr[2], lr[2], vr[2];
  kr[0] = *(const short8*)&KgH[srow * D_ + sc16];
  kr[1] = *(const short8*)&KgH[srow * D_ + sc16 + 8];
  lr[0] = *(const short8*)&KgL[srow * D_ + sc16];
  lr[1] = *(const short8*)&KgL[srow * D_ + sc16 + 8];
  vr[0] = *(const short8*)&Vg[srow * S_ + sc16];
  vr[1] = *(const short8*)&Vg[srow * S_ + sc16 + 8];

  for (int kt = 0; kt < kend; kt += 64) {
    block_sync();                            // previous tile fully consumed
    *(short8*)&Khi[srow * 72 + sc16]     = kr[0];
    *(short8*)&Khi[srow * 72 + sc16 + 8] = kr[1];
    *(short8*)&Klo[srow * 72 + sc16]     = lr[0];
    *(short8*)&Klo[srow * 72 + sc16 + 8] = lr[1];
    *(short8*)&Vt[srow * 72 + sc16]      = vr[0];
    *(short8*)&Vt[srow * 72 + sc16 + 8]  = vr[1];
    block_sync();
    if (kt + 64 < kend) {                    // prefetch next tile
      const int kn = kt + 64;
      kr[0] = *(const short8*)&KgH[(kn + srow) * D_ + sc16];
      kr[1] = *(const short8*)&KgH[(kn + srow) * D_ + sc16 + 8];
      lr[0] = *(const short8*)&KgL[(kn + srow) * D_ + sc16];
      lr[1] = *(const short8*)&KgL[(kn + srow) * D_ + sc16 + 8];
      vr[0] = *(const short8*)&Vg[srow * S_ + kn + sc16];
      vr[1] = *(const short8*)&Vg[srow * S_ + kn + sc16 + 8];
    }

    // ---- scores: S[16q x 64k] ----
    f32x4 sc[4];
#pragma unroll
    for (int kt16 = 0; kt16 < 4; ++kt16) {
      const int ko = (16 * kt16 + lc) * 72 + 8 * g;
      const short8 kh0 = *(const short8*)&Khi[ko];
      const short8 kh1 = *(const short8*)&Khi[ko + 32];
      const short8 kl0 = *(const short8*)&Klo[ko];
      const short8 kl1 = *(const short8*)&Klo[ko + 32];
      f32x4 a = {0.f, 0.f, 0.f, 0.f};
      a = __builtin_amdgcn_mfma_f32_16x16x32_bf16(qh[0], kh0, a, 0, 0, 0);
      a = __builtin_amdgcn_mfma_f32_16x16x32_bf16(qh[1], kh1, a, 0, 0, 0);
      a = __builtin_amdgcn_mfma_f32_16x16x32_bf16(qh[0], kl0, a, 0, 0, 0);
      a = __builtin_amdgcn_mfma_f32_16x16x32_bf16(qh[1], kl1, a, 0, 0, 0);
      a = __builtin_amdgcn_mfma_f32_16x16x32_bf16(ql[0], kh0, a, 0, 0, 0);
      a = __builtin_amdgcn_mfma_f32_16x16x32_bf16(ql[1], kh1, a, 0, 0, 0);
      sc[kt16] = a;
    }

    // ---- tail masking: compacted cols >= nk are padding (garbage K) ----
    if (kt + 64 > nk) {
#pragma unroll
      for (int kt16 = 0; kt16 < 4; ++kt16) {
        if (kt + 16 * kt16 + lc >= nk) {
          sc[kt16][0] = -1e20f; sc[kt16][1] = -1e20f;
          sc[kt16][2] = -1e20f; sc[kt16][3] = -1e20f;
        }
      }
    }

    // ---- online max + exp (max butterfly only; sum comes from MFMA) ----
    float al[4];
#pragma unroll
    for (int r = 0; r < 4; ++r) {
      float vv = fmaxf(fmaxf(sc[0][r], sc[1][r]), fmaxf(sc[2][r], sc[3][r]));
      vv = fmaxf(vv, __shfl_xor(vv, 1));
      vv = fmaxf(vv, __shfl_xor(vv, 2));
      vv = fmaxf(vv, __shfl_xor(vv, 4));
      vv = fmaxf(vv, __shfl_xor(vv, 8));
      const float mn = fmaxf(mst[r], vv);
      al[r] = __expf(mst[r] - mn);           // first tile: exp(-inf)=0
      mst[r] = mn;
    }
#pragma unroll
    for (int kt16 = 0; kt16 < 4; ++kt16) {
#pragma unroll
      for (int r = 0; r < 4; ++r)
        sc[kt16][r] = __expf(sc[kt16][r] - mst[r]);
    }
    const f32x4 alv = {al[0], al[1], al[2], al[3]};
    O[0] *= alv; O[1] *= alv; O[2] *= alv; O[3] *= alv;
    Ol *= alv;
    // P: C-layout regs -> bf16 LDS (A-layout source for PV)
#pragma unroll
    for (int kt16 = 0; kt16 < 4; ++kt16) {
#pragma unroll
      for (int r = 0; r < 4; ++r)
        Pw[(4 * g + r) * 72 + 16 * kt16 + lc] = (short)f2bf(sc[kt16][r]);
    }

    // ---- PV + denominator via ones ----
    short8 pa[2];
    pa[0] = *(const short8*)&Pw[lc * 72 + 8 * g];
    pa[1] = *(const short8*)&Pw[lc * 72 + 32 + 8 * g];
    Ol = __builtin_amdgcn_mfma_f32_16x16x32_bf16(pa[0], ones8, Ol, 0, 0, 0);
    Ol = __builtin_amdgcn_mfma_f32_16x16x32_bf16(pa[1], ones8, Ol, 0, 0, 0);
#pragma unroll
    for (int dt = 0; dt < 4; ++dt) {
      const int vo = (16 * dt + lc) * 72 + 8 * g;
      const short8 vb0 = *(const short8*)&Vt[vo];
      const short8 vb1 = *(const short8*)&Vt[vo + 32];
      O[dt] = __builtin_amdgcn_mfma_f32_16x16x32_bf16(pa[0], vb0, O[dt], 0, 0, 0);
      O[dt] = __builtin_amdgcn_mfma_f32_16x16x32_bf16(pa[1], vb1, O[dt], 0, 0, 0);
    }
  }

  // ---- epilogue: broadcast denominator (col 0 on lanes lc==0), normalize ----
#pragma unroll
  for (int r = 0; r < 4; ++r) {
    const float lv = __shfl(Ol[r], lane & 48);
    const float lir = 1.0f / lv;
    const int qrow = q0 + 16 * w + 4 * g + r;
    const size_t rowb = (size_t)(b * S_ + qrow) * E_ + hh * 64;
#pragma unroll
    for (int dt = 0; dt < 4; ++dt)
      AOHi[rowb + dt * 16 + lc] = f2bf(O[dt][r] * lir);
  }
}

// ---------------------------------------------------------------------------
// Kernel 3: output projection. v10: m97-style — BOTH operands staged by
// global_load_lds width=16 (no VMEM->VGPR round trip, no ds_writes), XOR
// swizzle chunk^=(row>>1)&3. Tile 64x128 (grid 64x8 = 512 blocks = 2/CU),
// 4 waves (2m x 2n), wave = 32x64 (acc[2][4]). LDS 12,288 B.
// ---------------------------------------------------------------------------
__global__ __launch_bounds__(256) void gemm_out_kernel(
    const u16* __restrict__ AHi,
    const u16* __restrict__ WHi,
    const float* __restrict__ bias, float* __restrict__ out)
{
  __shared__ __align__(16) short smem[6144];   // A[64][32] + B[128][32]
  short* Ah = smem;           // 4096 B
  short* Bh = smem + 2048;    // 8192 B

  const int t = threadIdx.x;
  const int m0 = blockIdx.x * 64;
  const int n0 = blockIdx.y * 128;
  const int w = t >> 6, lane = t & 63;
  const int g = lane >> 4, lc = lane & 15;
  const int wm = w & 1, wn = w >> 1;

  f32x4 acc[2][4];
#pragma unroll
  for (int i = 0; i < 2; ++i)
#pragma unroll
    for (int j = 0; j < 4; ++j) acc[i][j] = (f32x4){0.f, 0.f, 0.f, 0.f};

  for (int k0 = 0; k0 < E_; k0 += 32) {
    // stage: A 1 gload/wave, B 2 gloads/wave (pre-swizzled sources)
    {
      const int cA = w * 64 + lane;              // 0..255
      const int rowA = cA >> 2;
      const int subA = (cA & 3) ^ ((rowA >> 1) & 3);
      gload16(AHi + (size_t)(m0 + rowA) * E_ + k0 + subA * 8,
              (char*)Ah + w * 1024);
#pragma unroll
      for (int i = 0; i < 2; ++i) {
        const int c = (w * 2 + i) * 64 + lane;   // 0..511
        const int row = c >> 2;
        const int sub = (c & 3) ^ ((row >> 1) & 3);
        gload16(WHi + (size_t)(n0 + row) * E_ + k0 + sub * 8,
                (char*)Bh + (w * 2 + i) * 1024);
      }
    }
    __syncthreads();                 // vmcnt drain: tiles arrived

    short8 ah[2], bh[4];
#pragma unroll
    for (int mt = 0; mt < 2; ++mt) {
      const int row = wm * 32 + mt * 16 + lc;
      ah[mt] = *(const short8*)&Ah[row * 32 + ((g ^ ((row >> 1) & 3)) * 8)];
    }
#pragma unroll
    for (int nt = 0; nt < 4; ++nt) {
      const int row = wn * 64 + nt * 16 + lc;
      bh[nt] = *(const short8*)&Bh[row * 32 + ((g ^ ((row >> 1) & 3)) * 8)];
    }
#pragma unroll
    for (int mt = 0; mt < 2; ++mt)
#pragma unroll
      for (int nt = 0; nt < 4; ++nt)
        acc[mt][nt] = __builtin_amdgcn_mfma_f32_16x16x32_bf16(ah[mt], bh[nt], acc[mt][nt], 0, 0, 0);
    __syncthreads();                 // frags read -> safe to overwrite
  }

  float bs[4];
#pragma unroll
  for (int nt = 0; nt < 4; ++nt) bs[nt] = bias[n0 + wn * 64 + nt * 16 + lc];
#pragma unroll
  for (int nt = 0; nt < 4; ++nt) {
    const int nc = n0 + wn * 64 + nt * 16 + lc;
#pragma unroll
    for (int mt = 0; mt < 2; ++mt) {
#pragma unroll
      for (int r = 0; r < 4; ++r) {
        const int mrow = m0 + wm * 32 + mt * 16 + g * 4 + r;
        out[(size_t)mrow * E_ + nc] = acc[mt][nt][r] + bs[nt];
      }
    }
  }
}

// ---------------------------------------------------------------------------
extern "C" void kernel_launch(void* const* d_in, const int* in_sizes, int n_in,
                              void* d_out, int out_size, void* d_ws, size_t ws_size,
                              hipStream_t stream) {
  const float* q    = (const float*)d_in[0];
  const float* k    = (const float*)d_in[1];
  const float* v    = (const float*)d_in[2];
  const int*   mask = (const int*)d_in[3];
  const float* Wqkv = (const float*)d_in[4];
  const float* bqkv = (const float*)d_in[5];
  const float* Wout = (const float*)d_in[6];
  const float* bout = (const float*)d_in[7];
  float* out = (float*)d_out;

  // Workspace layout (64 MB).
  char* wsb = (char*)d_ws;
  u16* WqkvHi = (u16*)(wsb + 0);          //  6 MB
  u16* WqkvLo = (u16*)(wsb + 6291456);    //  6 MB
  u16* WoutHi = (u16*)(wsb + 12582912);   //  2 MB
  // WoutLo region (2 MB at 14680064) is scratch: split writes it, then the
  // scan kernel reuses the space for opos/nk (stream-ordered, safe).
  int* Opos   = (int*)(wsb + 14680064);   // 16 KB (B*S ints)
  int* Nk     = (int*)(wsb + 14680064 + 16384);  // 8 B
  u16* WoutLo = (u16*)(wsb + 14680064);   // (written then overwritten, unused)
  u16* QpHi   = (u16*)(wsb + 16777216);   //  8 MB
  u16* QpLo   = (u16*)(wsb + 25165824);   //  8 MB
  u16* KpHi   = (u16*)(wsb + 33554432);   //  8 MB
  u16* KpLo   = (u16*)(wsb + 41943040);   //  8 MB
  u16* Vp     = (u16*)(wsb + 50331648);   //  8 MB
  u16* AOHi   = (u16*)(wsb + 58720256);   //  8 MB

  hipLaunchKernelGGL(split_f32_kernel, dim3(3072), dim3(256), 0, stream,
                     Wqkv, WqkvHi, WqkvLo, 786432);
  hipLaunchKernelGGL(split_f32_kernel, dim3(1024), dim3(256), 0, stream,
                     Wout, WoutHi, WoutLo, 262144);
  hipLaunchKernelGGL(mask_scan_kernel, dim3(B_), dim3(256), 0, stream,
                     mask, Opos, Nk);
  // zero V so padded tail columns (>= nk) contribute exact 0 in PV
  hipMemsetAsync(Vp, 0, 8388608, stream);
  hipLaunchKernelGGL(gemm_qkv_kernel, dim3(M_ / 128, 24), dim3(256), 0, stream,
                     q, k, v, WqkvHi, WqkvLo, bqkv, Opos, Nk,
                     QpHi, QpLo, KpHi, KpLo, Vp);
  hipLaunchKernelGGL(attn_mfma_kernel, dim3(S_ / 64, B_ * H_), dim3(256), 0, stream,
                     QpHi, QpLo, KpHi, KpLo, Vp, Nk, AOHi);
  hipLaunchKernelGGL(gemm_out_kernel, dim3(M_ / 64, E_ / 128), dim3(256), 0, stream,
                     AOHi, WoutHi, bout, out);
}